// Round 1
// baseline (396.372 us; speedup 1.0000x reference)
//
#include <hip/hip_runtime.h>

// KAN layer: B=32768, D=256, K=10
// out[b] = wo2 . tanh( W2o-contraction(tanh(x*w1+b1)) + c ) + bo2
// where W2o[d,k,m] = sum_j w2[d,k,j]*wo1[d*K+j,m],
//       c[m] = bo1[m] + sum_{d,j} b2[d,j]*wo1[d*K+j,m]
//
// ws layout (floats):
//   [0, 30720)       Wt: per 128-d chunk, permuted rows: [chunk][slot][m][12]
//   [30720, 35840)   wb: [chunk][slot][k][2] = (w1,b1) pre-scaled by 2*log2(e)
//   [35840, 35850)   c[10]
//
// slot(d_loc) = (d_loc&31)*4 + (d_loc>>5)  so that at compute time,
// lane group g = lane&3 handling local-d i reads LDS row i*4+g
// (group row-stride 120 / 20 floats -> distinct banks, conflict-free).

#define LOG2E2 2.885390081777927f   // 2*log2(e)

#if __has_builtin(__builtin_amdgcn_exp2f)
#define EXP2F(x) __builtin_amdgcn_exp2f(x)
#else
#define EXP2F(x) __expf((x) * 0.6931471805599453f)
#endif

#if __has_builtin(__builtin_amdgcn_rcpf)
#define RCPF(x) __builtin_amdgcn_rcpf(x)
#else
#define RCPF(x) (1.0f / (x))
#endif

// t = 2*log2(e)*a  ->  tanh(a) = (2^t - 1)/(2^t + 1)
__device__ __forceinline__ float tanh_from_scaled(float t) {
    float e = EXP2F(t);
    return (e - 1.0f) * RCPF(e + 1.0f);
}

__global__ void kan_prep(const float* __restrict__ w1, const float* __restrict__ b1,
                         const float* __restrict__ w2, const float* __restrict__ b2,
                         const float* __restrict__ wo1, const float* __restrict__ bo1,
                         float* __restrict__ ws) {
    int gid = blockIdx.x * 256 + threadIdx.x;
    if (gid < 30720) {
        // Wt entries: gid -> (d, m, kk), kk in [0,12)
        int d = gid / 120;
        int rem = gid - d * 120;
        int m = rem / 12;
        int kk = rem - m * 12;
        float v = 0.0f;
        if (kk < 10) {
            const float* w2p = w2 + d * 100 + kk * 10;
            const float* wo1p = wo1 + d * 100;   // rows (d*10+j), col m
            #pragma unroll
            for (int j = 0; j < 10; ++j) v += w2p[j] * wo1p[j * 10 + m];
        }
        int chunk = d >> 7, dl = d & 127;
        int slot = (dl & 31) * 4 + (dl >> 5);
        ws[chunk * 15360 + slot * 120 + m * 12 + kk] = v;
    } else if (gid < 35840) {
        int idx = gid - 30720;          // [0, 5120)
        int pair = idx >> 1, which = idx & 1;
        int d = pair / 10, k = pair - d * 10;
        float v = (which ? b1 : w1)[d * 10 + k] * LOG2E2;
        int chunk = d >> 7, dl = d & 127;
        int slot = (dl & 31) * 4 + (dl >> 5);
        ws[30720 + chunk * 2560 + slot * 20 + k * 2 + which] = v;
    } else if (gid >= 35840 && gid < 35904) {
        // single wave (block 140, threads 0..63): compute c[10]
        int lane = gid - 35840;
        float cm[10];
        #pragma unroll
        for (int m = 0; m < 10; ++m) cm[m] = 0.0f;
        for (int r = lane; r < 2560; r += 64) {
            float bv = b2[r];
            const float* wp = wo1 + r * 10;
            #pragma unroll
            for (int m = 0; m < 10; ++m) cm[m] = fmaf(bv, wp[m], cm[m]);
        }
        #pragma unroll
        for (int s = 1; s < 64; s <<= 1) {
            #pragma unroll
            for (int m = 0; m < 10; ++m) cm[m] += __shfl_xor(cm[m], s);
        }
        if (lane < 10) ws[35840 + lane] = cm[lane] + bo1[lane];
    }
}

__device__ __forceinline__ void kan_body(float x0, int slot, float* acc,
                                         const float* ldsW, const float* ldsB) {
    const float4* wbp = (const float4*)(ldsB + slot * 20);
    float4 q0 = wbp[0], q1 = wbp[1], q2 = wbp[2], q3 = wbp[3], q4 = wbp[4];
    float h[10];
    h[0] = tanh_from_scaled(fmaf(x0, q0.x, q0.y));
    h[1] = tanh_from_scaled(fmaf(x0, q0.z, q0.w));
    h[2] = tanh_from_scaled(fmaf(x0, q1.x, q1.y));
    h[3] = tanh_from_scaled(fmaf(x0, q1.z, q1.w));
    h[4] = tanh_from_scaled(fmaf(x0, q2.x, q2.y));
    h[5] = tanh_from_scaled(fmaf(x0, q2.z, q2.w));
    h[6] = tanh_from_scaled(fmaf(x0, q3.x, q3.y));
    h[7] = tanh_from_scaled(fmaf(x0, q3.z, q3.w));
    h[8] = tanh_from_scaled(fmaf(x0, q4.x, q4.y));
    h[9] = tanh_from_scaled(fmaf(x0, q4.z, q4.w));
    const float* Wrow = ldsW + slot * 120;
    #pragma unroll
    for (int m = 0; m < 10; ++m) {
        const float4 a0 = *(const float4*)(Wrow + m * 12);
        const float4 a1 = *(const float4*)(Wrow + m * 12 + 4);
        const float4 a2 = *(const float4*)(Wrow + m * 12 + 8);
        float s = acc[m];
        s = fmaf(h[0], a0.x, s); s = fmaf(h[1], a0.y, s);
        s = fmaf(h[2], a0.z, s); s = fmaf(h[3], a0.w, s);
        s = fmaf(h[4], a1.x, s); s = fmaf(h[5], a1.y, s);
        s = fmaf(h[6], a1.z, s); s = fmaf(h[7], a1.w, s);
        s = fmaf(h[8], a2.x, s); s = fmaf(h[9], a2.y, s);
        acc[m] = s;
    }
}

__global__ __launch_bounds__(256, 2)
void kan_main(const float* __restrict__ x, const float* __restrict__ ws,
              const float* __restrict__ wo2, const float* __restrict__ bo2,
              float* __restrict__ out) {
    __shared__ float ldsW[15360];   // [slot 0..127][m 0..9][12]
    __shared__ float ldsB[2560];    // [slot 0..127][k 0..9][2]

    const int t = threadIdx.x;
    const int lane = t & 63;
    const int wave = t >> 6;
    const int g = lane & 3;                       // d-group within wave
    const int row = blockIdx.x * 64 + wave * 16 + (lane >> 2);
    const float* xrow = x + (size_t)row * 256;

    float acc[10];
    #pragma unroll
    for (int m = 0; m < 10; ++m) acc[m] = 0.0f;

    for (int chunk = 0; chunk < 2; ++chunk) {
        if (chunk) __syncthreads();   // compute done before LDS overwrite

        const float* xp = xrow + chunk * 128 + g * 32;
        float4 xq = *(const float4*)(xp);   // prefetch first quad (hides under staging)

        // stage weights chunk into LDS (linear coalesced copy)
        const float4* srcW = (const float4*)(ws + chunk * 15360);
        float4* dW = (float4*)ldsW;
        for (int idx = t; idx < 3840; idx += 256) dW[idx] = srcW[idx];
        const float4* srcB = (const float4*)(ws + 30720 + chunk * 2560);
        float4* dB = (float4*)ldsB;
        for (int idx = t; idx < 640; idx += 256) dB[idx] = srcB[idx];
        __syncthreads();

        #pragma unroll 2
        for (int io = 0; io < 8; ++io) {
            float4 xn = make_float4(0.f, 0.f, 0.f, 0.f);
            if (io < 7) xn = *(const float4*)(xp + (io + 1) * 4);
            int sbase = io * 16 + g;            // slot = (io*4+ii)*4 + g
            kan_body(xq.x, sbase + 0,  acc, ldsW, ldsB);
            kan_body(xq.y, sbase + 4,  acc, ldsW, ldsB);
            kan_body(xq.z, sbase + 8,  acc, ldsW, ldsB);
            kan_body(xq.w, sbase + 12, acc, ldsW, ldsB);
            xq = xn;
        }
    }

    // reduce the 4 d-groups per row
    #pragma unroll
    for (int m = 0; m < 10; ++m) {
        acc[m] += __shfl_xor(acc[m], 1);
        acc[m] += __shfl_xor(acc[m], 2);
    }

    if (g == 0) {
        const float* c = ws + 35840;
        float o = bo2[0];
        #pragma unroll
        for (int m = 0; m < 10; ++m) {
            float u = tanh_from_scaled(LOG2E2 * (acc[m] + c[m]));
            o = fmaf(u, wo2[m], o);
        }
        out[row] = o;
    }
}

extern "C" void kernel_launch(void* const* d_in, const int* in_sizes, int n_in,
                              void* d_out, int out_size, void* d_ws, size_t ws_size,
                              hipStream_t stream) {
    const float* x   = (const float*)d_in[0];
    const float* w1  = (const float*)d_in[1];
    const float* b1  = (const float*)d_in[2];
    const float* w2  = (const float*)d_in[3];
    const float* b2  = (const float*)d_in[4];
    const float* wo1 = (const float*)d_in[5];
    const float* bo1 = (const float*)d_in[6];
    const float* wo2 = (const float*)d_in[7];
    const float* bo2 = (const float*)d_in[8];
    float* out = (float*)d_out;
    float* ws  = (float*)d_ws;

    hipLaunchKernelGGL(kan_prep, dim3(141), dim3(256), 0, stream,
                       w1, b1, w2, b2, wo1, bo1, ws);
    hipLaunchKernelGGL(kan_main, dim3(512), dim3(256), 0, stream,
                       x, ws, wo2, bo2, out);
}

// Round 2
// 89.924 us; speedup vs baseline: 4.4078x; 4.4078x over previous
//
#include <hip/hip_runtime.h>

// KAN layer: B=32768, D=256, K=10
// out[b] = wo2 . tanh( W2o-contraction(tanh(x*w1+b1)) + c ) + bo2
// where W2o[d,k,m] = sum_j w2[d,k,j]*wo1[d*K+j,m],
//       c[m] = bo1[m] + sum_{d,j} b2[d,j]*wo1[d*K+j,m]
//
// ws layout (floats):
//   [0, 30720)       Wt: per 128-d chunk, permuted rows: [chunk][slot][m][12]
//   [30720, 35840)   wb: [chunk][slot][k][2] = (w1,b1) pre-scaled by 2*log2(e)
//   [35840, 35850)   c[10]
//
// slot(d_loc) = (d_loc&31)*4 + (d_loc>>5): lane group g = lane&3 handling
// local-d i reads LDS row i*4+g (distinct banks across groups).
//
// ROUND 2: all compute written as macros on named scalars, direct __shared__
// access, zero local arrays, zero helper-function boundaries -> no scratch.

#define LOG2E2 2.885390081777927f   // 2*log2(e)

#if __has_builtin(__builtin_amdgcn_exp2f)
#define EXP2F(x) __builtin_amdgcn_exp2f(x)
#else
#define EXP2F(x) __expf((x) * 0.6931471805599453f)
#endif

#if __has_builtin(__builtin_amdgcn_rcpf)
#define RCPF(x) __builtin_amdgcn_rcpf(x)
#else
#define RCPF(x) (1.0f / (x))
#endif

// DST = tanh(a) where T = 2*log2(e)*a  ->  (2^T - 1)/(2^T + 1)
#define TANHS(DST, T) do { float _e = EXP2F(T); DST = (_e - 1.0f) * RCPF(_e + 1.0f); } while (0)

__global__ void kan_prep(const float* __restrict__ w1, const float* __restrict__ b1,
                         const float* __restrict__ w2, const float* __restrict__ b2,
                         const float* __restrict__ wo1, const float* __restrict__ bo1,
                         float* __restrict__ ws) {
    int gid = blockIdx.x * 256 + threadIdx.x;
    if (gid < 30720) {
        // Wt entries: gid -> (d, m, kk), kk in [0,12)
        int d = gid / 120;
        int rem = gid - d * 120;
        int m = rem / 12;
        int kk = rem - m * 12;
        float v = 0.0f;
        if (kk < 10) {
            const float* w2p = w2 + d * 100 + kk * 10;
            const float* wo1p = wo1 + d * 100;   // rows (d*10+j), col m
            #pragma unroll
            for (int j = 0; j < 10; ++j) v += w2p[j] * wo1p[j * 10 + m];
        }
        int chunk = d >> 7, dl = d & 127;
        int slot = (dl & 31) * 4 + (dl >> 5);
        ws[chunk * 15360 + slot * 120 + m * 12 + kk] = v;
    } else if (gid < 35840) {
        int idx = gid - 30720;          // [0, 5120)
        int pair = idx >> 1, which = idx & 1;
        int d = pair / 10, k = pair - d * 10;
        float v = (which ? b1 : w1)[d * 10 + k] * LOG2E2;
        int chunk = d >> 7, dl = d & 127;
        int slot = (dl & 31) * 4 + (dl >> 5);
        ws[30720 + chunk * 2560 + slot * 20 + k * 2 + which] = v;
    } else if (gid >= 35840 && gid < 35904) {
        // single wave: compute c[10]
        int lane = gid - 35840;
        float c0 = 0.f, c1 = 0.f, c2 = 0.f, c3 = 0.f, c4 = 0.f;
        float c5 = 0.f, c6 = 0.f, c7 = 0.f, c8 = 0.f, c9 = 0.f;
        for (int r = lane; r < 2560; r += 64) {
            float bv = b2[r];
            const float* wp = wo1 + r * 10;
            c0 = fmaf(bv, wp[0], c0); c1 = fmaf(bv, wp[1], c1);
            c2 = fmaf(bv, wp[2], c2); c3 = fmaf(bv, wp[3], c3);
            c4 = fmaf(bv, wp[4], c4); c5 = fmaf(bv, wp[5], c5);
            c6 = fmaf(bv, wp[6], c6); c7 = fmaf(bv, wp[7], c7);
            c8 = fmaf(bv, wp[8], c8); c9 = fmaf(bv, wp[9], c9);
        }
        #pragma unroll
        for (int s = 1; s < 64; s <<= 1) {
            c0 += __shfl_xor(c0, s); c1 += __shfl_xor(c1, s);
            c2 += __shfl_xor(c2, s); c3 += __shfl_xor(c3, s);
            c4 += __shfl_xor(c4, s); c5 += __shfl_xor(c5, s);
            c6 += __shfl_xor(c6, s); c7 += __shfl_xor(c7, s);
            c8 += __shfl_xor(c8, s); c9 += __shfl_xor(c9, s);
        }
        if (lane == 0) {
            ws[35840 + 0] = c0 + bo1[0]; ws[35840 + 1] = c1 + bo1[1];
            ws[35840 + 2] = c2 + bo1[2]; ws[35840 + 3] = c3 + bo1[3];
            ws[35840 + 4] = c4 + bo1[4]; ws[35840 + 5] = c5 + bo1[5];
            ws[35840 + 6] = c6 + bo1[6]; ws[35840 + 7] = c7 + bo1[7];
            ws[35840 + 8] = c8 + bo1[8]; ws[35840 + 9] = c9 + bo1[9];
        }
    }
}

// one m-column: 12-float LDS row (last 2 pad), 10 FMAs into ACC
#define KAN_M(ACC, OFF) do { \
    float4 _a0 = *(const float4*)&ldsW[_wb + (OFF)]; \
    float4 _a1 = *(const float4*)&ldsW[_wb + (OFF) + 4]; \
    float4 _a2 = *(const float4*)&ldsW[_wb + (OFF) + 8]; \
    ACC = fmaf(_h0, _a0.x, ACC); ACC = fmaf(_h1, _a0.y, ACC); \
    ACC = fmaf(_h2, _a0.z, ACC); ACC = fmaf(_h3, _a0.w, ACC); \
    ACC = fmaf(_h4, _a1.x, ACC); ACC = fmaf(_h5, _a1.y, ACC); \
    ACC = fmaf(_h6, _a1.z, ACC); ACC = fmaf(_h7, _a1.w, ACC); \
    ACC = fmaf(_h8, _a2.x, ACC); ACC = fmaf(_h9, _a2.y, ACC); \
} while (0)

// one x-element against one d-slot: 10 tanh + 100 FMA
#define KAN_ELEM(X, SLOT) do { \
    int _s = (SLOT); \
    float _x = (X); \
    float4 _q0 = *(const float4*)&ldsB[_s * 20]; \
    float4 _q1 = *(const float4*)&ldsB[_s * 20 + 4]; \
    float4 _q2 = *(const float4*)&ldsB[_s * 20 + 8]; \
    float4 _q3 = *(const float4*)&ldsB[_s * 20 + 12]; \
    float4 _q4 = *(const float4*)&ldsB[_s * 20 + 16]; \
    float _h0, _h1, _h2, _h3, _h4, _h5, _h6, _h7, _h8, _h9; \
    TANHS(_h0, fmaf(_x, _q0.x, _q0.y)); \
    TANHS(_h1, fmaf(_x, _q0.z, _q0.w)); \
    TANHS(_h2, fmaf(_x, _q1.x, _q1.y)); \
    TANHS(_h3, fmaf(_x, _q1.z, _q1.w)); \
    TANHS(_h4, fmaf(_x, _q2.x, _q2.y)); \
    TANHS(_h5, fmaf(_x, _q2.z, _q2.w)); \
    TANHS(_h6, fmaf(_x, _q3.x, _q3.y)); \
    TANHS(_h7, fmaf(_x, _q3.z, _q3.w)); \
    TANHS(_h8, fmaf(_x, _q4.x, _q4.y)); \
    TANHS(_h9, fmaf(_x, _q4.z, _q4.w)); \
    int _wb = _s * 120; \
    KAN_M(acc0, 0);  KAN_M(acc1, 12);  KAN_M(acc2, 24);  KAN_M(acc3, 36); \
    KAN_M(acc4, 48); KAN_M(acc5, 60);  KAN_M(acc6, 72);  KAN_M(acc7, 84); \
    KAN_M(acc8, 96); KAN_M(acc9, 108); \
} while (0)

__global__ __launch_bounds__(256, 2)
void kan_main(const float* __restrict__ x, const float* __restrict__ ws,
              const float* __restrict__ wo2, const float* __restrict__ bo2,
              float* __restrict__ out) {
    __shared__ float ldsW[15360];   // [slot 0..127][m 0..9][12]
    __shared__ float ldsB[2560];    // [slot 0..127][k 0..9][2]

    const int t = threadIdx.x;
    const int lane = t & 63;
    const int wave = t >> 6;
    const int g = lane & 3;                       // d-group within wave
    const int row = blockIdx.x * 64 + wave * 16 + (lane >> 2);
    const float* xrow = x + (size_t)row * 256;

    float acc0 = 0.f, acc1 = 0.f, acc2 = 0.f, acc3 = 0.f, acc4 = 0.f;
    float acc5 = 0.f, acc6 = 0.f, acc7 = 0.f, acc8 = 0.f, acc9 = 0.f;

    for (int chunk = 0; chunk < 2; ++chunk) {
        if (chunk) __syncthreads();   // compute done before LDS overwrite

        // stage weights chunk into LDS (linear coalesced copy)
        {
            const float4* srcW = (const float4*)(ws + chunk * 15360);
            float4* dW = (float4*)ldsW;
            for (int idx = t; idx < 3840; idx += 256) dW[idx] = srcW[idx];
            const float4* srcB = (const float4*)(ws + 30720 + chunk * 2560);
            float4* dB = (float4*)ldsB;
            for (int idx = t; idx < 640; idx += 256) dB[idx] = srcB[idx];
        }
        __syncthreads();

        const float* xp = xrow + chunk * 128 + g * 32;
        for (int io = 0; io < 8; ++io) {
            float4 xq = *(const float4*)(xp + io * 4);
            int sbase = io * 16 + g;            // slot = (io*4+ii)*4 + g
            KAN_ELEM(xq.x, sbase + 0);
            KAN_ELEM(xq.y, sbase + 4);
            KAN_ELEM(xq.z, sbase + 8);
            KAN_ELEM(xq.w, sbase + 12);
        }
    }

    // reduce the 4 d-groups per row (groups differ in lane bits 0..1)
    acc0 += __shfl_xor(acc0, 1); acc0 += __shfl_xor(acc0, 2);
    acc1 += __shfl_xor(acc1, 1); acc1 += __shfl_xor(acc1, 2);
    acc2 += __shfl_xor(acc2, 1); acc2 += __shfl_xor(acc2, 2);
    acc3 += __shfl_xor(acc3, 1); acc3 += __shfl_xor(acc3, 2);
    acc4 += __shfl_xor(acc4, 1); acc4 += __shfl_xor(acc4, 2);
    acc5 += __shfl_xor(acc5, 1); acc5 += __shfl_xor(acc5, 2);
    acc6 += __shfl_xor(acc6, 1); acc6 += __shfl_xor(acc6, 2);
    acc7 += __shfl_xor(acc7, 1); acc7 += __shfl_xor(acc7, 2);
    acc8 += __shfl_xor(acc8, 1); acc8 += __shfl_xor(acc8, 2);
    acc9 += __shfl_xor(acc9, 1); acc9 += __shfl_xor(acc9, 2);

    if (g == 0) {
        const float* c = ws + 35840;
        float o = bo2[0];
        float u;
        TANHS(u, LOG2E2 * (acc0 + c[0])); o = fmaf(u, wo2[0], o);
        TANHS(u, LOG2E2 * (acc1 + c[1])); o = fmaf(u, wo2[1], o);
        TANHS(u, LOG2E2 * (acc2 + c[2])); o = fmaf(u, wo2[2], o);
        TANHS(u, LOG2E2 * (acc3 + c[3])); o = fmaf(u, wo2[3], o);
        TANHS(u, LOG2E2 * (acc4 + c[4])); o = fmaf(u, wo2[4], o);
        TANHS(u, LOG2E2 * (acc5 + c[5])); o = fmaf(u, wo2[5], o);
        TANHS(u, LOG2E2 * (acc6 + c[6])); o = fmaf(u, wo2[6], o);
        TANHS(u, LOG2E2 * (acc7 + c[7])); o = fmaf(u, wo2[7], o);
        TANHS(u, LOG2E2 * (acc8 + c[8])); o = fmaf(u, wo2[8], o);
        TANHS(u, LOG2E2 * (acc9 + c[9])); o = fmaf(u, wo2[9], o);
        out[row] = o;
    }
}

extern "C" void kernel_launch(void* const* d_in, const int* in_sizes, int n_in,
                              void* d_out, int out_size, void* d_ws, size_t ws_size,
                              hipStream_t stream) {
    const float* x   = (const float*)d_in[0];
    const float* w1  = (const float*)d_in[1];
    const float* b1  = (const float*)d_in[2];
    const float* w2  = (const float*)d_in[3];
    const float* b2  = (const float*)d_in[4];
    const float* wo1 = (const float*)d_in[5];
    const float* bo1 = (const float*)d_in[6];
    const float* wo2 = (const float*)d_in[7];
    const float* bo2 = (const float*)d_in[8];
    float* out = (float*)d_out;
    float* ws  = (float*)d_ws;

    hipLaunchKernelGGL(kan_prep, dim3(141), dim3(256), 0, stream,
                       w1, b1, w2, b2, wo1, bo1, ws);
    hipLaunchKernelGGL(kan_main, dim3(512), dim3(256), 0, stream,
                       x, ws, wo2, bo2, out);
}

// Round 3
// 68.697 us; speedup vs baseline: 5.7699x; 1.3090x over previous
//
#include <hip/hip_runtime.h>

// KAN layer: B=32768, D=256, K=10
// out[b] = wo2 . tanh( W2o-contraction(tanh(x*w1+b1)) + c ) + bo2
// where W2o[d,k,m] = sum_j w2[d,k,j]*wo1[d*K+j,m],
//       c[m] = bo1[m] + sum_{d,j} b2[d,j]*wo1[d*K+j,m]
//
// ws layout (floats):
//   [0, 31744)        W: [d 0..255][m 0..9][12] rows padded to 124 floats
//   [31744, 36864)    wb: [d][k][2] = (w1,b1) pre-scaled by 2*log2(e)
//   [36864, 36874)    c[10]
//
// ROUND 3: register-block R=4 rows per thread so each weight ds_read_b128
// feeds 4x the FMAs (round 2 was LDS-issue-bound: 294M b128 ~= 90us).
// 16 d-groups per wave; W row stride 124 floats -> start banks 28g mod 32
// (8 distinct, 2-way alias = free). All state in named scalars.

#define LOG2E2 2.885390081777927f   // 2*log2(e)

#if __has_builtin(__builtin_amdgcn_exp2f)
#define EXP2F(x) __builtin_amdgcn_exp2f(x)
#else
#define EXP2F(x) __expf((x) * 0.6931471805599453f)
#endif

#if __has_builtin(__builtin_amdgcn_rcpf)
#define RCPF(x) __builtin_amdgcn_rcpf(x)
#else
#define RCPF(x) (1.0f / (x))
#endif

// DST = tanh(a) where T = 2*log2(e)*a  ->  (2^T - 1)/(2^T + 1)
#define TANHS(DST, T) do { float _e = EXP2F(T); DST = (_e - 1.0f) * RCPF(_e + 1.0f); } while (0)

__global__ void kan_prep(const float* __restrict__ w1, const float* __restrict__ b1,
                         const float* __restrict__ w2, const float* __restrict__ b2,
                         const float* __restrict__ wo1, const float* __restrict__ bo1,
                         float* __restrict__ ws) {
    int gid = blockIdx.x * 256 + threadIdx.x;
    if (gid < 31744) {
        // W entries: gid -> d*124 + m*12 + kk
        int d = gid / 124;
        int rem = gid - d * 124;
        int m = rem / 12;
        int kk = rem - m * 12;
        float v = 0.0f;
        if (m < 10 && kk < 10) {
            const float* w2p = w2 + d * 100 + kk * 10;
            const float* wo1p = wo1 + d * 100;   // rows (d*10+j), col m
            #pragma unroll
            for (int j = 0; j < 10; ++j) v += w2p[j] * wo1p[j * 10 + m];
        }
        ws[gid] = v;
    } else if (gid < 36864) {
        int idx = gid - 31744;          // [0, 5120) -> d*20 + k*2 + which
        int d = idx / 20;
        int rem2 = idx - d * 20;
        int k = rem2 >> 1, which = rem2 & 1;
        ws[gid] = (which ? b1 : w1)[d * 10 + k] * LOG2E2;
    } else if (gid < 36928) {
        // single wave: compute c[10]
        int lane = gid - 36864;
        float c0 = 0.f, c1 = 0.f, c2 = 0.f, c3 = 0.f, c4 = 0.f;
        float c5 = 0.f, c6 = 0.f, c7 = 0.f, c8 = 0.f, c9 = 0.f;
        for (int r = lane; r < 2560; r += 64) {
            float bv = b2[r];
            const float* wp = wo1 + r * 10;
            c0 = fmaf(bv, wp[0], c0); c1 = fmaf(bv, wp[1], c1);
            c2 = fmaf(bv, wp[2], c2); c3 = fmaf(bv, wp[3], c3);
            c4 = fmaf(bv, wp[4], c4); c5 = fmaf(bv, wp[5], c5);
            c6 = fmaf(bv, wp[6], c6); c7 = fmaf(bv, wp[7], c7);
            c8 = fmaf(bv, wp[8], c8); c9 = fmaf(bv, wp[9], c9);
        }
        #pragma unroll
        for (int s = 1; s < 64; s <<= 1) {
            c0 += __shfl_xor(c0, s); c1 += __shfl_xor(c1, s);
            c2 += __shfl_xor(c2, s); c3 += __shfl_xor(c3, s);
            c4 += __shfl_xor(c4, s); c5 += __shfl_xor(c5, s);
            c6 += __shfl_xor(c6, s); c7 += __shfl_xor(c7, s);
            c8 += __shfl_xor(c8, s); c9 += __shfl_xor(c9, s);
        }
        if (lane == 0) {
            ws[36864 + 0] = c0 + bo1[0]; ws[36864 + 1] = c1 + bo1[1];
            ws[36864 + 2] = c2 + bo1[2]; ws[36864 + 3] = c3 + bo1[3];
            ws[36864 + 4] = c4 + bo1[4]; ws[36864 + 5] = c5 + bo1[5];
            ws[36864 + 6] = c6 + bo1[6]; ws[36864 + 7] = c7 + bo1[7];
            ws[36864 + 8] = c8 + bo1[8]; ws[36864 + 9] = c9 + bo1[9];
        }
    }
}

// 10 tanh activations for row R (uses xc##R, q0..q4)
#define HROW(R) \
    TANHS(H##R##0, fmaf(xc##R, q0.x, q0.y)); \
    TANHS(H##R##1, fmaf(xc##R, q0.z, q0.w)); \
    TANHS(H##R##2, fmaf(xc##R, q1.x, q1.y)); \
    TANHS(H##R##3, fmaf(xc##R, q1.z, q1.w)); \
    TANHS(H##R##4, fmaf(xc##R, q2.x, q2.y)); \
    TANHS(H##R##5, fmaf(xc##R, q2.z, q2.w)); \
    TANHS(H##R##6, fmaf(xc##R, q3.x, q3.y)); \
    TANHS(H##R##7, fmaf(xc##R, q3.z, q3.w)); \
    TANHS(H##R##8, fmaf(xc##R, q4.x, q4.y)); \
    TANHS(H##R##9, fmaf(xc##R, q4.z, q4.w));

// 10 FMAs of row R into accumulator column M (uses w0,w1,w2)
#define MFMA_ROW(R, M) \
    A##R##M = fmaf(H##R##0, w0.x, A##R##M); \
    A##R##M = fmaf(H##R##1, w0.y, A##R##M); \
    A##R##M = fmaf(H##R##2, w0.z, A##R##M); \
    A##R##M = fmaf(H##R##3, w0.w, A##R##M); \
    A##R##M = fmaf(H##R##4, w1.x, A##R##M); \
    A##R##M = fmaf(H##R##5, w1.y, A##R##M); \
    A##R##M = fmaf(H##R##6, w1.z, A##R##M); \
    A##R##M = fmaf(H##R##7, w1.w, A##R##M); \
    A##R##M = fmaf(H##R##8, w2.x, A##R##M); \
    A##R##M = fmaf(H##R##9, w2.y, A##R##M);

// one m-column: 3 LDS b128 reads, then 4 rows x 10 FMA
#define MCOL(M) { \
    float4 w0 = *(const float4*)&ldsW[wbase + (M)*12]; \
    float4 w1 = *(const float4*)&ldsW[wbase + (M)*12 + 4]; \
    float4 w2 = *(const float4*)&ldsW[wbase + (M)*12 + 8]; \
    MFMA_ROW(0, M) MFMA_ROW(1, M) MFMA_ROW(2, M) MFMA_ROW(3, M) }

// reduce acc over the 16 d-groups (lane bits 0..3)
#define RED(R, M) \
    A##R##M += __shfl_xor(A##R##M, 1); A##R##M += __shfl_xor(A##R##M, 2); \
    A##R##M += __shfl_xor(A##R##M, 4); A##R##M += __shfl_xor(A##R##M, 8);

#define EPI1(R, M) \
    TANHS(u, LOG2E2 * (A##R##M + c##M)); o = fmaf(u, v##M, o);

#define EPI(R) { \
    float o = b2v; float u; \
    EPI1(R, 0) EPI1(R, 1) EPI1(R, 2) EPI1(R, 3) EPI1(R, 4) \
    EPI1(R, 5) EPI1(R, 6) EPI1(R, 7) EPI1(R, 8) EPI1(R, 9) \
    out[rowbase + R] = o; }

__global__ __launch_bounds__(256, 2)
void kan_main(const float* __restrict__ x, const float* __restrict__ ws,
              const float* __restrict__ wo2, const float* __restrict__ bo2,
              float* __restrict__ out) {
    __shared__ float ldsW[15872];   // [d_local 0..127][124]
    __shared__ float ldsB[2560];    // [d_local 0..127][k 0..9][2]

    const int t = threadIdx.x;
    const int lane = t & 63;
    const int wave = t >> 6;
    const int g = lane & 15;                      // d-group within wave
    const int rl = lane >> 4;                     // rowlane 0..3
    const int rowbase = blockIdx.x * 64 + wave * 16 + rl * 4;
    const float* xr = x + (size_t)rowbase * 256 + g;

    float A00=0.f,A01=0.f,A02=0.f,A03=0.f,A04=0.f,A05=0.f,A06=0.f,A07=0.f,A08=0.f,A09=0.f;
    float A10=0.f,A11=0.f,A12=0.f,A13=0.f,A14=0.f,A15=0.f,A16=0.f,A17=0.f,A18=0.f,A19=0.f;
    float A20=0.f,A21=0.f,A22=0.f,A23=0.f,A24=0.f,A25=0.f,A26=0.f,A27=0.f,A28=0.f,A29=0.f;
    float A30=0.f,A31=0.f,A32=0.f,A33=0.f,A34=0.f,A35=0.f,A36=0.f,A37=0.f,A38=0.f,A39=0.f;

    for (int chunk = 0; chunk < 2; ++chunk) {
        if (chunk) __syncthreads();   // compute done before LDS overwrite

        // stage weights chunk into LDS (linear coalesced copy)
        {
            const float4* srcW = (const float4*)(ws + chunk * 15872);
            float4* dW = (float4*)ldsW;
            for (int idx = t; idx < 3968; idx += 256) dW[idx] = srcW[idx];
            const float4* srcB = (const float4*)(ws + 31744 + chunk * 2560);
            float4* dB = (float4*)ldsB;
            for (int idx = t; idx < 640; idx += 256) dB[idx] = srcB[idx];
        }
        __syncthreads();

        const float* xp = xr + chunk * 128;
        float xc0 = xp[0], xc1 = xp[256], xc2 = xp[512], xc3 = xp[768];

        for (int i = 0; i < 8; ++i) {
            int ip = ((i + 1) & 7) * 16;     // prefetch next i's x (wraps harmlessly)
            float xn0 = xp[ip], xn1 = xp[ip + 256], xn2 = xp[ip + 512], xn3 = xp[ip + 768];

            const int s = i * 16 + g;        // d_local
            const int bbase = s * 20;
            float4 q0 = *(const float4*)&ldsB[bbase];
            float4 q1 = *(const float4*)&ldsB[bbase + 4];
            float4 q2 = *(const float4*)&ldsB[bbase + 8];
            float4 q3 = *(const float4*)&ldsB[bbase + 12];
            float4 q4 = *(const float4*)&ldsB[bbase + 16];

            float H00,H01,H02,H03,H04,H05,H06,H07,H08,H09;
            float H10,H11,H12,H13,H14,H15,H16,H17,H18,H19;
            float H20,H21,H22,H23,H24,H25,H26,H27,H28,H29;
            float H30,H31,H32,H33,H34,H35,H36,H37,H38,H39;
            HROW(0) HROW(1) HROW(2) HROW(3)

            const int wbase = s * 124;
            MCOL(0) MCOL(1) MCOL(2) MCOL(3) MCOL(4)
            MCOL(5) MCOL(6) MCOL(7) MCOL(8) MCOL(9)

            xc0 = xn0; xc1 = xn1; xc2 = xn2; xc3 = xn3;
        }
    }

    RED(0,0) RED(0,1) RED(0,2) RED(0,3) RED(0,4) RED(0,5) RED(0,6) RED(0,7) RED(0,8) RED(0,9)
    RED(1,0) RED(1,1) RED(1,2) RED(1,3) RED(1,4) RED(1,5) RED(1,6) RED(1,7) RED(1,8) RED(1,9)
    RED(2,0) RED(2,1) RED(2,2) RED(2,3) RED(2,4) RED(2,5) RED(2,6) RED(2,7) RED(2,8) RED(2,9)
    RED(3,0) RED(3,1) RED(3,2) RED(3,3) RED(3,4) RED(3,5) RED(3,6) RED(3,7) RED(3,8) RED(3,9)

    if (g == 0) {
        const float* c = ws + 36864;
        float c0=c[0],c1=c[1],c2=c[2],c3=c[3],c4=c[4],c5=c[5],c6=c[6],c7=c[7],c8=c[8],c9=c[9];
        float v0=wo2[0],v1=wo2[1],v2=wo2[2],v3=wo2[3],v4=wo2[4];
        float v5=wo2[5],v6=wo2[6],v7=wo2[7],v8=wo2[8],v9=wo2[9];
        float b2v = bo2[0];
        EPI(0) EPI(1) EPI(2) EPI(3)
    }
}

extern "C" void kernel_launch(void* const* d_in, const int* in_sizes, int n_in,
                              void* d_out, int out_size, void* d_ws, size_t ws_size,
                              hipStream_t stream) {
    const float* x   = (const float*)d_in[0];
    const float* w1  = (const float*)d_in[1];
    const float* b1  = (const float*)d_in[2];
    const float* w2  = (const float*)d_in[3];
    const float* b2  = (const float*)d_in[4];
    const float* wo1 = (const float*)d_in[5];
    const float* bo1 = (const float*)d_in[6];
    const float* wo2 = (const float*)d_in[7];
    const float* bo2 = (const float*)d_in[8];
    float* out = (float*)d_out;
    float* ws  = (float*)d_ws;

    hipLaunchKernelGGL(kan_prep, dim3(145), dim3(256), 0, stream,
                       w1, b1, w2, b2, wo1, bo1, ws);
    hipLaunchKernelGGL(kan_main, dim3(512), dim3(256), 0, stream,
                       x, ws, wo2, bo2, out);
}

// Round 7
// 55.359 us; speedup vs baseline: 7.1600x; 1.2409x over previous
//
#include <hip/hip_runtime.h>
#include <hip/hip_bf16.h>

// KAN layer: B=32768, D=256, K=10 — MFMA formulation.
// out[b] = wo2 . tanh( LOG2E2^-1 * ( MFMA_contract(h, Wf) * LOG2E2 + cs ) ) + bo2
// h[b,kk] = tanh(x[b,d]*w1s[kk] + b1s[kk]), kk = d*10+k, Wf[kk,m] = sum_j w2[d,k,j]*wo1[d*10+j,m]
// cs[m] = LOG2E2*(bo1[m] + sum b2*wo1)
//
// MFMA mfma_f32_16x16x32_bf16; wave = one 16-row tile; 80 MFMA steps cover kk=0..2559:
// per 16-d group q: 4 "main" steps (lane-slot (hi,v) -> d = q*16+hi*4+j, k=v in 0..7)
// + 1 "tail" step (d = q*16+hi*4+(v>>1), k = 8+(v&1)). A and B use the same slot->kk
// map, so the HW k-permutation cancels. B-fragments, w1s/b1s prebuilt by prep in ws,
// byte-identical layout to LDS -> staging is one linear float4 copy.
//
// ws/LDS byte layout:
//   [0,     20480)  WB  f32 [256 d][20]  : [d][2v]=w1s, [d][2v+1]=b1s (v=0..7), pads
//   [20480, 24576)  TWB f32 [16 q][4 hi][8 v][2] : tail (w,b)
//   [24576, 69632)  WM  bf16 [256 d][11 m][8 k]  : Wf[d*10+k][m], k=0..7 (m slot 10 = pad)
//   [69632, 79872)  WTL bf16 [16 q][4 hi][10 m][8 v] : tail Wf
//   [79872, 79920)  CS  f32 [12] : cs[m] (10..11 pad)
//
// ROUND 7: fix prep TWB bound — was gid<31744 (2048 ids) for a 1024-entry
// region: the overflow wrote garbage (from OOB w1/b1 reads, d up to 511) into
// ws bytes 24576..28671 = start of WM -> NaN bf16 weights -> NaN output.
// Now TWB is gid in [29696,30720), cs-wave at [30720,30784). No other change.

#define LOG2E2 2.885390081777927f   // 2*log2(e)

#if __has_builtin(__builtin_amdgcn_exp2f)
#define EXP2F(x) __builtin_amdgcn_exp2f(x)
#else
#define EXP2F(x) __expf((x) * 0.6931471805599453f)
#endif
#if __has_builtin(__builtin_amdgcn_rcpf)
#define RCPF(x) __builtin_amdgcn_rcpf(x)
#else
#define RCPF(x) (1.0f / (x))
#endif
#define TANHS(DST, T) do { float _e = EXP2F(T); DST = (_e - 1.0f) * RCPF(_e + 1.0f); } while (0)

typedef __attribute__((ext_vector_type(8))) short short8v;
typedef __attribute__((ext_vector_type(4))) float f32x4;
union U8 { short8v v; __hip_bfloat162 p[4]; };

__device__ __forceinline__ ushort f2bf(float f) {
    union { float f; unsigned u; } a; a.f = f;
    unsigned u = a.u;
    u += 0x7FFF + ((u >> 16) & 1);
    return (ushort)(u >> 16);
}

__global__ void kan_prep(const float* __restrict__ w1, const float* __restrict__ b1,
                         const float* __restrict__ w2, const float* __restrict__ b2,
                         const float* __restrict__ wo1, const float* __restrict__ bo1,
                         float* __restrict__ ws) {
    int gid = blockIdx.x * 256 + threadIdx.x;
    float* wsF = ws;
    ushort* wsU = (ushort*)ws;
    if (gid < 25600) {
        // Wf[d,k,m] = sum_j w2[d,k,j]*wo1[d*10+j, m]
        int m = gid % 10;
        int k = (gid / 10) % 10;
        int d = gid / 100;
        const float* w2p = w2 + d * 100 + k * 10;
        const float* wop = wo1 + d * 100 + m;
        float v = 0.f;
        #pragma unroll
        for (int j = 0; j < 10; ++j) v = fmaf(w2p[j], wop[j * 10], v);
        ushort hv = f2bf(v);
        if (k < 8) {
            wsU[12288 + (d * 11 + m) * 8 + k] = hv;
        } else {
            int s = d >> 4, hi = (d >> 2) & 3, vv = ((d & 3) << 1) | (k - 8);
            wsU[34816 + ((s * 4 + hi) * 10 + m) * 8 + vv] = hv;
        }
    } else if (gid < 29696) {
        // WB: id = d*16 + r; r = 2v+which
        int id = gid - 25600;
        int d = id >> 4, r = id & 15;
        int v = r >> 1;
        wsF[d * 20 + r] = ((r & 1) ? b1 : w1)[d * 10 + v] * LOG2E2;
    } else if (gid < 30720) {
        // TWB: id = slot*2 + which, slot = (q*4+hi)*8 + v, 512 slots total
        int id = gid - 29696;
        int which = id & 1, slot = id >> 1;
        int v = slot & 7, hi = (slot >> 3) & 3, s = slot >> 5;
        int d = s * 16 + hi * 4 + (v >> 1);
        int k = 8 + (v & 1);
        wsF[5120 + slot * 2 + which] = ((which) ? b1 : w1)[d * 10 + k] * LOG2E2;
    } else if (gid < 30784) {
        // one wave: cs[10]
        int lane = gid - 30720;
        float c0 = 0.f, c1 = 0.f, c2 = 0.f, c3 = 0.f, c4 = 0.f;
        float c5 = 0.f, c6 = 0.f, c7 = 0.f, c8 = 0.f, c9 = 0.f;
        for (int r = lane; r < 2560; r += 64) {
            float bv = b2[r];
            const float* wp = wo1 + r * 10;
            c0 = fmaf(bv, wp[0], c0); c1 = fmaf(bv, wp[1], c1);
            c2 = fmaf(bv, wp[2], c2); c3 = fmaf(bv, wp[3], c3);
            c4 = fmaf(bv, wp[4], c4); c5 = fmaf(bv, wp[5], c5);
            c6 = fmaf(bv, wp[6], c6); c7 = fmaf(bv, wp[7], c7);
            c8 = fmaf(bv, wp[8], c8); c9 = fmaf(bv, wp[9], c9);
        }
        #pragma unroll
        for (int s = 1; s < 64; s <<= 1) {
            c0 += __shfl_xor(c0, s); c1 += __shfl_xor(c1, s);
            c2 += __shfl_xor(c2, s); c3 += __shfl_xor(c3, s);
            c4 += __shfl_xor(c4, s); c5 += __shfl_xor(c5, s);
            c6 += __shfl_xor(c6, s); c7 += __shfl_xor(c7, s);
            c8 += __shfl_xor(c8, s); c9 += __shfl_xor(c9, s);
        }
        if (lane == 0) {
            wsF[19968 + 0] = LOG2E2 * (c0 + bo1[0]);
            wsF[19968 + 1] = LOG2E2 * (c1 + bo1[1]);
            wsF[19968 + 2] = LOG2E2 * (c2 + bo1[2]);
            wsF[19968 + 3] = LOG2E2 * (c3 + bo1[3]);
            wsF[19968 + 4] = LOG2E2 * (c4 + bo1[4]);
            wsF[19968 + 5] = LOG2E2 * (c5 + bo1[5]);
            wsF[19968 + 6] = LOG2E2 * (c6 + bo1[6]);
            wsF[19968 + 7] = LOG2E2 * (c7 + bo1[7]);
            wsF[19968 + 8] = LOG2E2 * (c8 + bo1[8]);
            wsF[19968 + 9] = LOG2E2 * (c9 + bo1[9]);
        }
    }
}

// one main MFMA step: d = qb + hi4 + J, k = 0..7
#define MAINSTEP(J, XC) { \
    const int d_ = qb + hi4 + (J); \
    const float* wb_ = ldsF + d_ * 20; \
    const float4 p0 = *(const float4*)(wb_); \
    const float4 p1 = *(const float4*)(wb_ + 4); \
    const float4 p2 = *(const float4*)(wb_ + 8); \
    const float4 p3 = *(const float4*)(wb_ + 12); \
    float h0, h1, h2, h3, h4, h5, h6, h7; \
    TANHS(h0, fmaf(XC, p0.x, p0.y)); TANHS(h1, fmaf(XC, p0.z, p0.w)); \
    TANHS(h2, fmaf(XC, p1.x, p1.y)); TANHS(h3, fmaf(XC, p1.z, p1.w)); \
    TANHS(h4, fmaf(XC, p2.x, p2.y)); TANHS(h5, fmaf(XC, p2.z, p2.w)); \
    TANHS(h6, fmaf(XC, p3.x, p3.y)); TANHS(h7, fmaf(XC, p3.z, p3.w)); \
    U8 u_; \
    u_.p[0] = __float22bfloat162_rn(make_float2(h0, h1)); \
    u_.p[1] = __float22bfloat162_rn(make_float2(h2, h3)); \
    u_.p[2] = __float22bfloat162_rn(make_float2(h4, h5)); \
    u_.p[3] = __float22bfloat162_rn(make_float2(h6, h7)); \
    const short8v bf_ = *(const short8v*)(ldsU + 12288 + d_ * 88 + meff8); \
    acc = __builtin_amdgcn_mfma_f32_16x16x32_bf16(u_.v, bf_, acc, 0, 0, 0); \
}

// tail MFMA step for group q: d = qb + hi4 + (v>>1), k = 8+(v&1)
#define TAILSTEP { \
    const float* tw_ = ldsF + 5120 + qb * 4 + hi16; \
    const float4 p0 = *(const float4*)(tw_); \
    const float4 p1 = *(const float4*)(tw_ + 4); \
    const float4 p2 = *(const float4*)(tw_ + 8); \
    const float4 p3 = *(const float4*)(tw_ + 12); \
    float h0, h1, h2, h3, h4, h5, h6, h7; \
    TANHS(h0, fmaf(xq.x, p0.x, p0.y)); TANHS(h1, fmaf(xq.x, p0.z, p0.w)); \
    TANHS(h2, fmaf(xq.y, p1.x, p1.y)); TANHS(h3, fmaf(xq.y, p1.z, p1.w)); \
    TANHS(h4, fmaf(xq.z, p2.x, p2.y)); TANHS(h5, fmaf(xq.z, p2.z, p2.w)); \
    TANHS(h6, fmaf(xq.w, p3.x, p3.y)); TANHS(h7, fmaf(xq.w, p3.z, p3.w)); \
    U8 u_; \
    u_.p[0] = __float22bfloat162_rn(make_float2(h0, h1)); \
    u_.p[1] = __float22bfloat162_rn(make_float2(h2, h3)); \
    u_.p[2] = __float22bfloat162_rn(make_float2(h4, h5)); \
    u_.p[3] = __float22bfloat162_rn(make_float2(h6, h7)); \
    const short8v bf_ = *(const short8v*)(ldsU + 34816 + qb * 20 + hi80 + meff8); \
    acc = __builtin_amdgcn_mfma_f32_16x16x32_bf16(u_.v, bf_, acc, 0, 0, 0); \
}

__global__ __launch_bounds__(256, 2)
void kan_main(const float* __restrict__ x, const float* __restrict__ ws,
              const float* __restrict__ wo2, const float* __restrict__ bo2,
              float* __restrict__ out) {
    __shared__ float4 ldsRaw[4995];            // 79920 B
    float* ldsF = (float*)ldsRaw;
    const ushort* ldsU = (const ushort*)ldsRaw;

    const int t = threadIdx.x;
    {
        const float4* src = (const float4*)ws;
        for (int i = t; i < 4995; i += 256) ldsRaw[i] = src[i];
    }
    __syncthreads();

    const int lane = t & 63;
    const int wave = t >> 6;
    const int m = lane & 15;                   // A-row within tile AND C/D col
    const int hi = lane >> 4;
    const int hi4 = hi * 4, hi16 = hi * 16, hi80 = hi * 80;
    const int meff8 = ((m < 10) ? m : 0) * 8;
    const int base = (blockIdx.x * 4 + wave) * 16;
    const float* xr = x + (size_t)(base + m) * 256;

    f32x4 acc = {0.f, 0.f, 0.f, 0.f};

    #pragma unroll 4
    for (int q = 0; q < 16; ++q) {
        const int qb = q * 16;
        const float4 xq = *(const float4*)(xr + qb + hi4);
        MAINSTEP(0, xq.x)
        MAINSTEP(1, xq.y)
        MAINSTEP(2, xq.z)
        MAINSTEP(3, xq.w)
        TAILSTEP
    }

    // epilogue: acc[r] = OUT[base + hi*4 + r][m]; outer tanh + wo2 dot across m-lanes
    const float csm = ldsF[19968 + (meff8 >> 3)];
    const float wo2m = (m < 10) ? wo2[m] : 0.f;
    const float bo2v = bo2[0];

    float a0 = (m < 10) ? acc[0] : 0.f;
    float a1 = (m < 10) ? acc[1] : 0.f;
    float a2 = (m < 10) ? acc[2] : 0.f;
    float a3 = (m < 10) ? acc[3] : 0.f;
    float u0, u1, u2, u3;
    TANHS(u0, fmaf(LOG2E2, a0, csm));
    TANHS(u1, fmaf(LOG2E2, a1, csm));
    TANHS(u2, fmaf(LOG2E2, a2, csm));
    TANHS(u3, fmaf(LOG2E2, a3, csm));
    float s0 = u0 * wo2m, s1 = u1 * wo2m, s2 = u2 * wo2m, s3 = u3 * wo2m;
    s0 += __shfl_xor(s0, 1); s0 += __shfl_xor(s0, 2); s0 += __shfl_xor(s0, 4); s0 += __shfl_xor(s0, 8);
    s1 += __shfl_xor(s1, 1); s1 += __shfl_xor(s1, 2); s1 += __shfl_xor(s1, 4); s1 += __shfl_xor(s1, 8);
    s2 += __shfl_xor(s2, 1); s2 += __shfl_xor(s2, 2); s2 += __shfl_xor(s2, 4); s2 += __shfl_xor(s2, 8);
    s3 += __shfl_xor(s3, 1); s3 += __shfl_xor(s3, 2); s3 += __shfl_xor(s3, 4); s3 += __shfl_xor(s3, 8);
    if (m == 0) {
        out[base + hi4 + 0] = s0 + bo2v;
        out[base + hi4 + 1] = s1 + bo2v;
        out[base + hi4 + 2] = s2 + bo2v;
        out[base + hi4 + 3] = s3 + bo2v;
    }
}

extern "C" void kernel_launch(void* const* d_in, const int* in_sizes, int n_in,
                              void* d_out, int out_size, void* d_ws, size_t ws_size,
                              hipStream_t stream) {
    const float* x   = (const float*)d_in[0];
    const float* w1  = (const float*)d_in[1];
    const float* b1  = (const float*)d_in[2];
    const float* w2  = (const float*)d_in[3];
    const float* b2  = (const float*)d_in[4];
    const float* wo1 = (const float*)d_in[5];
    const float* bo1 = (const float*)d_in[6];
    const float* wo2 = (const float*)d_in[7];
    const float* bo2 = (const float*)d_in[8];
    float* out = (float*)d_out;
    float* ws  = (float*)d_ws;

    hipLaunchKernelGGL(kan_prep, dim3(121), dim3(256), 0, stream,
                       w1, b1, w2, b2, wo1, bo1, ws);
    hipLaunchKernelGGL(kan_main, dim3(512), dim3(256), 0, stream,
                       x, ws, wo2, bo2, out);
}

// Round 9
// 51.564 us; speedup vs baseline: 7.6870x; 1.0736x over previous
//
#include <hip/hip_runtime.h>
#include <hip/hip_bf16.h>

// KAN layer: B=32768, D=256, K=10 — MFMA formulation.
// out[b] = wo2 . tanh( LOG2E2^-1 * ( MFMA_contract(h, Wf) * LOG2E2 + cs ) ) + bo2
// h[b,kk] = tanh(x[b,d]*w1s[kk] + b1s[kk]), kk = d*10+k, Wf[kk,m] = sum_j w2[d,k,j]*wo1[d*10+j,m]
// cs[m] = LOG2E2*(bo1[m] + sum b2*wo1)
//
// MFMA mfma_f32_16x16x32_bf16; wave = one 16-row tile; 80 MFMA steps cover kk=0..2559:
// per 16-d group q: 4 "main" steps (lane-slot (hi,v) -> d = q*16+hi*4+j, k=v in 0..7)
// + 1 "tail" step (d = q*16+hi*4+(v>>1), k = 8+(v&1)). A and B use the same slot->kk
// map, so the HW k-permutation cancels. B-fragments, w1s/b1s prebuilt by prep in ws,
// byte-identical layout to LDS -> staging is one linear float4 copy.
//
// ws/LDS byte layout:
//   [0,     20480)  WB  f32 [256 d][20]  : [d][2v]=w1s, [d][2v+1]=b1s (v=0..7), pads
//   [20480, 24576)  TWB f32 [16 q][4 hi][8 v][2] : tail (w,b)
//   [24576, 69632)  WM  bf16 [256 d][11 m][8 k]  : Wf[d*10+k][m], k=0..7 (m slot 10 = pad)
//   [69632, 79872)  WTL bf16 [16 q][4 hi][10 m][8 v] : tail Wf
//   [79872, 79920)  CS  f32 [12] : cs[m] (10..11 pad)
//
// ROUND 9: same as round 8's intent (kill the U8-union scratch that made
// round 7 latency-bound at 52us / 46MB HBM writes), but the packing now uses
// inline-asm v_cvt_pk_bf16_f32 (2 f32 -> u32 of 2 bf16, RNE) + bit_cast of
// uint4v->short8v. No class types, registers only. (__builtin_bit_cast from
// __hip_bfloat162 was ill-formed: not trivially copyable.)

#define LOG2E2 2.885390081777927f   // 2*log2(e)

#if __has_builtin(__builtin_amdgcn_exp2f)
#define EXP2F(x) __builtin_amdgcn_exp2f(x)
#else
#define EXP2F(x) __expf((x) * 0.6931471805599453f)
#endif
#if __has_builtin(__builtin_amdgcn_rcpf)
#define RCPF(x) __builtin_amdgcn_rcpf(x)
#else
#define RCPF(x) (1.0f / (x))
#endif
#define TANHS(DST, T) do { float _e = EXP2F(T); DST = (_e - 1.0f) * RCPF(_e + 1.0f); } while (0)

typedef __attribute__((ext_vector_type(8))) short short8v;
typedef __attribute__((ext_vector_type(4))) float f32x4;
typedef __attribute__((ext_vector_type(4))) unsigned uint4v;

__device__ __forceinline__ unsigned cvt_pk_bf16(float lo, float hi) {
    unsigned r;
    asm("v_cvt_pk_bf16_f32 %0, %1, %2" : "=v"(r) : "v"(lo), "v"(hi));
    return r;
}

// pack h0..h7 (named floats in scope) into a short8v of bf16, registers only
#define PACK8(DST) { \
    uint4v _uu; \
    _uu.x = cvt_pk_bf16(h0, h1); \
    _uu.y = cvt_pk_bf16(h2, h3); \
    _uu.z = cvt_pk_bf16(h4, h5); \
    _uu.w = cvt_pk_bf16(h6, h7); \
    DST = __builtin_bit_cast(short8v, _uu); \
}

__device__ __forceinline__ ushort f2bf(float f) {
    union { float f; unsigned u; } a; a.f = f;
    unsigned u = a.u;
    u += 0x7FFF + ((u >> 16) & 1);
    return (ushort)(u >> 16);
}

__global__ void kan_prep(const float* __restrict__ w1, const float* __restrict__ b1,
                         const float* __restrict__ w2, const float* __restrict__ b2,
                         const float* __restrict__ wo1, const float* __restrict__ bo1,
                         float* __restrict__ ws) {
    int gid = blockIdx.x * 256 + threadIdx.x;
    float* wsF = ws;
    ushort* wsU = (ushort*)ws;
    if (gid < 25600) {
        // Wf[d,k,m] = sum_j w2[d,k,j]*wo1[d*10+j, m]
        int m = gid % 10;
        int k = (gid / 10) % 10;
        int d = gid / 100;
        const float* w2p = w2 + d * 100 + k * 10;
        const float* wop = wo1 + d * 100 + m;
        float v = 0.f;
        #pragma unroll
        for (int j = 0; j < 10; ++j) v = fmaf(w2p[j], wop[j * 10], v);
        ushort hv = f2bf(v);
        if (k < 8) {
            wsU[12288 + (d * 11 + m) * 8 + k] = hv;
        } else {
            int s = d >> 4, hi = (d >> 2) & 3, vv = ((d & 3) << 1) | (k - 8);
            wsU[34816 + ((s * 4 + hi) * 10 + m) * 8 + vv] = hv;
        }
    } else if (gid < 29696) {
        // WB: id = d*16 + r; r = 2v+which
        int id = gid - 25600;
        int d = id >> 4, r = id & 15;
        int v = r >> 1;
        wsF[d * 20 + r] = ((r & 1) ? b1 : w1)[d * 10 + v] * LOG2E2;
    } else if (gid < 30720) {
        // TWB: id = slot*2 + which, slot = (q*4+hi)*8 + v, 512 slots total
        int id = gid - 29696;
        int which = id & 1, slot = id >> 1;
        int v = slot & 7, hi = (slot >> 3) & 3, s = slot >> 5;
        int d = s * 16 + hi * 4 + (v >> 1);
        int k = 8 + (v & 1);
        wsF[5120 + slot * 2 + which] = ((which) ? b1 : w1)[d * 10 + k] * LOG2E2;
    } else if (gid < 30784) {
        // one wave: cs[10]
        int lane = gid - 30720;
        float c0 = 0.f, c1 = 0.f, c2 = 0.f, c3 = 0.f, c4 = 0.f;
        float c5 = 0.f, c6 = 0.f, c7 = 0.f, c8 = 0.f, c9 = 0.f;
        for (int r = lane; r < 2560; r += 64) {
            float bv = b2[r];
            const float* wp = wo1 + r * 10;
            c0 = fmaf(bv, wp[0], c0); c1 = fmaf(bv, wp[1], c1);
            c2 = fmaf(bv, wp[2], c2); c3 = fmaf(bv, wp[3], c3);
            c4 = fmaf(bv, wp[4], c4); c5 = fmaf(bv, wp[5], c5);
            c6 = fmaf(bv, wp[6], c6); c7 = fmaf(bv, wp[7], c7);
            c8 = fmaf(bv, wp[8], c8); c9 = fmaf(bv, wp[9], c9);
        }
        #pragma unroll
        for (int s = 1; s < 64; s <<= 1) {
            c0 += __shfl_xor(c0, s); c1 += __shfl_xor(c1, s);
            c2 += __shfl_xor(c2, s); c3 += __shfl_xor(c3, s);
            c4 += __shfl_xor(c4, s); c5 += __shfl_xor(c5, s);
            c6 += __shfl_xor(c6, s); c7 += __shfl_xor(c7, s);
            c8 += __shfl_xor(c8, s); c9 += __shfl_xor(c9, s);
        }
        if (lane == 0) {
            wsF[19968 + 0] = LOG2E2 * (c0 + bo1[0]);
            wsF[19968 + 1] = LOG2E2 * (c1 + bo1[1]);
            wsF[19968 + 2] = LOG2E2 * (c2 + bo1[2]);
            wsF[19968 + 3] = LOG2E2 * (c3 + bo1[3]);
            wsF[19968 + 4] = LOG2E2 * (c4 + bo1[4]);
            wsF[19968 + 5] = LOG2E2 * (c5 + bo1[5]);
            wsF[19968 + 6] = LOG2E2 * (c6 + bo1[6]);
            wsF[19968 + 7] = LOG2E2 * (c7 + bo1[7]);
            wsF[19968 + 8] = LOG2E2 * (c8 + bo1[8]);
            wsF[19968 + 9] = LOG2E2 * (c9 + bo1[9]);
        }
    }
}

// one main MFMA step: d = qb + hi4 + J, k = 0..7
#define MAINSTEP(J, XC) { \
    const int d_ = qb + hi4 + (J); \
    const float* wb_ = ldsF + d_ * 20; \
    const float4 p0 = *(const float4*)(wb_); \
    const float4 p1 = *(const float4*)(wb_ + 4); \
    const float4 p2 = *(const float4*)(wb_ + 8); \
    const float4 p3 = *(const float4*)(wb_ + 12); \
    float h0, h1, h2, h3, h4, h5, h6, h7; \
    TANHS(h0, fmaf(XC, p0.x, p0.y)); TANHS(h1, fmaf(XC, p0.z, p0.w)); \
    TANHS(h2, fmaf(XC, p1.x, p1.y)); TANHS(h3, fmaf(XC, p1.z, p1.w)); \
    TANHS(h4, fmaf(XC, p2.x, p2.y)); TANHS(h5, fmaf(XC, p2.z, p2.w)); \
    TANHS(h6, fmaf(XC, p3.x, p3.y)); TANHS(h7, fmaf(XC, p3.z, p3.w)); \
    short8v av_; PACK8(av_) \
    const short8v bf_ = *(const short8v*)(ldsU + 12288 + d_ * 88 + meff8); \
    acc = __builtin_amdgcn_mfma_f32_16x16x32_bf16(av_, bf_, acc, 0, 0, 0); \
}

// tail MFMA step for group q: d = qb + hi4 + (v>>1), k = 8+(v&1)
#define TAILSTEP { \
    const float* tw_ = ldsF + 5120 + qb * 4 + hi16; \
    const float4 p0 = *(const float4*)(tw_); \
    const float4 p1 = *(const float4*)(tw_ + 4); \
    const float4 p2 = *(const float4*)(tw_ + 8); \
    const float4 p3 = *(const float4*)(tw_ + 12); \
    float h0, h1, h2, h3, h4, h5, h6, h7; \
    TANHS(h0, fmaf(xq.x, p0.x, p0.y)); TANHS(h1, fmaf(xq.x, p0.z, p0.w)); \
    TANHS(h2, fmaf(xq.y, p1.x, p1.y)); TANHS(h3, fmaf(xq.y, p1.z, p1.w)); \
    TANHS(h4, fmaf(xq.z, p2.x, p2.y)); TANHS(h5, fmaf(xq.z, p2.z, p2.w)); \
    TANHS(h6, fmaf(xq.w, p3.x, p3.y)); TANHS(h7, fmaf(xq.w, p3.z, p3.w)); \
    short8v av_; PACK8(av_) \
    const short8v bf_ = *(const short8v*)(ldsU + 34816 + qb * 20 + hi80 + meff8); \
    acc = __builtin_amdgcn_mfma_f32_16x16x32_bf16(av_, bf_, acc, 0, 0, 0); \
}

__global__ __launch_bounds__(256, 2)
void kan_main(const float* __restrict__ x, const float* __restrict__ ws,
              const float* __restrict__ wo2, const float* __restrict__ bo2,
              float* __restrict__ out) {
    __shared__ float4 ldsRaw[4995];            // 79920 B
    float* ldsF = (float*)ldsRaw;
    const ushort* ldsU = (const ushort*)ldsRaw;

    const int t = threadIdx.x;
    {
        const float4* src = (const float4*)ws;
        for (int i = t; i < 4995; i += 256) ldsRaw[i] = src[i];
    }
    __syncthreads();

    const int lane = t & 63;
    const int wave = t >> 6;
    const int m = lane & 15;                   // A-row within tile AND C/D col
    const int hi = lane >> 4;
    const int hi4 = hi * 4, hi16 = hi * 16, hi80 = hi * 80;
    const int meff8 = ((m < 10) ? m : 0) * 8;
    const int base = (blockIdx.x * 4 + wave) * 16;
    const float* xr = x + (size_t)(base + m) * 256;

    f32x4 acc = {0.f, 0.f, 0.f, 0.f};

    #pragma unroll 4
    for (int q = 0; q < 16; ++q) {
        const int qb = q * 16;
        const float4 xq = *(const float4*)(xr + qb + hi4);
        MAINSTEP(0, xq.x)
        MAINSTEP(1, xq.y)
        MAINSTEP(2, xq.z)
        MAINSTEP(3, xq.w)
        TAILSTEP
    }

    // epilogue: acc[r] = OUT[base + hi*4 + r][m]; outer tanh + wo2 dot across m-lanes
    const float csm = ldsF[19968 + (meff8 >> 3)];
    const float wo2m = (m < 10) ? wo2[m] : 0.f;
    const float bo2v = bo2[0];

    float a0 = (m < 10) ? acc[0] : 0.f;
    float a1 = (m < 10) ? acc[1] : 0.f;
    float a2 = (m < 10) ? acc[2] : 0.f;
    float a3 = (m < 10) ? acc[3] : 0.f;
    float u0, u1, u2, u3;
    TANHS(u0, fmaf(LOG2E2, a0, csm));
    TANHS(u1, fmaf(LOG2E2, a1, csm));
    TANHS(u2, fmaf(LOG2E2, a2, csm));
    TANHS(u3, fmaf(LOG2E2, a3, csm));
    float s0 = u0 * wo2m, s1 = u1 * wo2m, s2 = u2 * wo2m, s3 = u3 * wo2m;
    s0 += __shfl_xor(s0, 1); s0 += __shfl_xor(s0, 2); s0 += __shfl_xor(s0, 4); s0 += __shfl_xor(s0, 8);
    s1 += __shfl_xor(s1, 1); s1 += __shfl_xor(s1, 2); s1 += __shfl_xor(s1, 4); s1 += __shfl_xor(s1, 8);
    s2 += __shfl_xor(s2, 1); s2 += __shfl_xor(s2, 2); s2 += __shfl_xor(s2, 4); s2 += __shfl_xor(s2, 8);
    s3 += __shfl_xor(s3, 1); s3 += __shfl_xor(s3, 2); s3 += __shfl_xor(s3, 4); s3 += __shfl_xor(s3, 8);
    if (m == 0) {
        out[base + hi4 + 0] = s0 + bo2v;
        out[base + hi4 + 1] = s1 + bo2v;
        out[base + hi4 + 2] = s2 + bo2v;
        out[base + hi4 + 3] = s3 + bo2v;
    }
}

extern "C" void kernel_launch(void* const* d_in, const int* in_sizes, int n_in,
                              void* d_out, int out_size, void* d_ws, size_t ws_size,
                              hipStream_t stream) {
    const float* x   = (const float*)d_in[0];
    const float* w1  = (const float*)d_in[1];
    const float* b1  = (const float*)d_in[2];
    const float* w2  = (const float*)d_in[3];
    const float* b2  = (const float*)d_in[4];
    const float* wo1 = (const float*)d_in[5];
    const float* bo1 = (const float*)d_in[6];
    const float* wo2 = (const float*)d_in[7];
    const float* bo2 = (const float*)d_in[8];
    float* out = (float*)d_out;
    float* ws  = (float*)d_ws;

    hipLaunchKernelGGL(kan_prep, dim3(121), dim3(256), 0, stream,
                       w1, b1, w2, b2, wo1, bo1, ws);
    hipLaunchKernelGGL(kan_main, dim3(512), dim3(256), 0, stream,
                       x, ws, wo2, bo2, out);
}

// Round 12
// 46.983 us; speedup vs baseline: 8.4365x; 1.0975x over previous
//
#include <hip/hip_runtime.h>
#include <hip/hip_bf16.h>

// KAN layer: B=32768, D=256, K=10 — MFMA + split-D (2 halves) + 2 row-tiles/wave.
// Round 12: identical resubmit of rounds 10/11 (container died before the
// kernel ran, both times). Design: round 9 was LDS-issue-bound (400 b128/wave
// feeding 1 MFMA tile each). Now each wave computes TWO 16-row accumulators
// sharing every LDS read, over HALF the d-range; per-half f32 partials go to
// ws; kan_epi reduces halves + outer tanh + wo2 dot.
//
// slot->kk map (verified r7/r9): main step (d, k=v in 0..7) with d = qb+hi*4+J;
// tail step d = qb+hi*4+(v>>1), k = 8+(v&1). A and B use the same map so the
// HW k-permutation cancels.
//
// ws layout (floats):
//   per half h (at h*9984):
//     [0,2560)    WBh  f32 [128 dl][20]: (w1s,b1s) pairs k=0..7 (16 used, 20 stride)
//     [2560,3072) TWBh f32 [8 q][4 hi][8 v][2]: tail (w,b)
//     [3072,8704) WMh  bf16 [128 dl][11 m][8 k] (ushort idx 6144 + dl*88 + m*8 + k)
//     [8704,9984) WTLh bf16 [8 q][4 hi][10 m][8 v] (ushort idx 17408 + (q*4+hi)*80 + m*8 + v)
//   [19968,19978) CS f32: cs[m] = LOG2E2*(bo1[m]+sum b2*wo1)
//   [20480, 20480+2*393216) P f32 [2 h][32768 row][12]: partial contractions
//   (ws_size ~256 MB per round-9 poison counters -> plenty)

#define LOG2E2 2.885390081777927f   // 2*log2(e)

#if __has_builtin(__builtin_amdgcn_exp2f)
#define EXP2F(x) __builtin_amdgcn_exp2f(x)
#else
#define EXP2F(x) __expf((x) * 0.6931471805599453f)
#endif
#if __has_builtin(__builtin_amdgcn_rcpf)
#define RCPF(x) __builtin_amdgcn_rcpf(x)
#else
#define RCPF(x) (1.0f / (x))
#endif
// tanh(a) with t = 2*log2(e)*a: 1 - 2/(2^t+1)  (4 instrs: exp2, add, rcp, fma)
#define TANHS(DST, T) do { float _e = EXP2F(T); DST = fmaf(-2.0f, RCPF(_e + 1.0f), 1.0f); } while (0)

typedef __attribute__((ext_vector_type(8))) short short8v;
typedef __attribute__((ext_vector_type(4))) float f32x4;
typedef __attribute__((ext_vector_type(4))) unsigned uint4v;

__device__ __forceinline__ unsigned cvt_pk_bf16(float lo, float hi) {
    unsigned r;
    asm("v_cvt_pk_bf16_f32 %0, %1, %2" : "=v"(r) : "v"(lo), "v"(hi));
    return r;
}

#define PACK8(DST) { \
    uint4v _uu; \
    _uu.x = cvt_pk_bf16(h0, h1); \
    _uu.y = cvt_pk_bf16(h2, h3); \
    _uu.z = cvt_pk_bf16(h4, h5); \
    _uu.w = cvt_pk_bf16(h6, h7); \
    DST = __builtin_bit_cast(short8v, _uu); \
}

__device__ __forceinline__ ushort f2bf(float f) {
    union { float f; unsigned u; } a; a.f = f;
    unsigned u = a.u;
    u += 0x7FFF + ((u >> 16) & 1);
    return (ushort)(u >> 16);
}

__global__ void kan_prep(const float* __restrict__ w1, const float* __restrict__ b1,
                         const float* __restrict__ w2, const float* __restrict__ b2,
                         const float* __restrict__ wo1, const float* __restrict__ bo1,
                         float* __restrict__ ws) {
    int gid = blockIdx.x * 256 + threadIdx.x;
    float* wsF = ws;
    ushort* wsU = (ushort*)ws;
    if (gid < 25600) {
        // Wf[d,k,m] = sum_j w2[d,k,j]*wo1[d*10+j, m]
        int m = gid % 10;
        int k = (gid / 10) % 10;
        int d = gid / 100;
        const float* w2p = w2 + d * 100 + k * 10;
        const float* wop = wo1 + d * 100 + m;
        float v = 0.f;
        #pragma unroll
        for (int j = 0; j < 10; ++j) v = fmaf(w2p[j], wop[j * 10], v);
        ushort hv = f2bf(v);
        int h = d >> 7, dl = d & 127;
        if (k < 8) {
            wsU[h * 19968 + 6144 + (dl * 11 + m) * 8 + k] = hv;
        } else {
            int ql = (d >> 4) & 7, hi = (d >> 2) & 3, vv = ((d & 3) << 1) | (k - 8);
            wsU[h * 19968 + 17408 + ((ql * 4 + hi) * 10 + m) * 8 + vv] = hv;
        }
    } else if (gid < 29696) {
        // WB: id = d*16 + r; r = 2v+which, v=0..7
        int id = gid - 25600;
        int d = id >> 4, r = id & 15;
        int v = r >> 1;
        int h = d >> 7, dl = d & 127;
        wsF[h * 9984 + dl * 20 + r] = ((r & 1) ? b1 : w1)[d * 10 + v] * LOG2E2;
    } else if (gid < 30720) {
        // TWB: id = slot*2 + which, slot = (qg*4+hi)*8 + v, qg=0..15
        int id = gid - 29696;
        int which = id & 1, slot = id >> 1;
        int v = slot & 7, hi = (slot >> 3) & 3, qg = slot >> 5;
        int d = qg * 16 + hi * 4 + (v >> 1);
        int k = 8 + (v & 1);
        int h = qg >> 3, ql = qg & 7;
        wsF[h * 9984 + 2560 + ((ql * 4 + hi) * 8 + v) * 2 + which] =
            ((which) ? b1 : w1)[d * 10 + k] * LOG2E2;
    } else if (gid < 30784) {
        // one wave: cs[10]
        int lane = gid - 30720;
        float c0 = 0.f, c1 = 0.f, c2 = 0.f, c3 = 0.f, c4 = 0.f;
        float c5 = 0.f, c6 = 0.f, c7 = 0.f, c8 = 0.f, c9 = 0.f;
        for (int r = lane; r < 2560; r += 64) {
            float bv = b2[r];
            const float* wp = wo1 + r * 10;
            c0 = fmaf(bv, wp[0], c0); c1 = fmaf(bv, wp[1], c1);
            c2 = fmaf(bv, wp[2], c2); c3 = fmaf(bv, wp[3], c3);
            c4 = fmaf(bv, wp[4], c4); c5 = fmaf(bv, wp[5], c5);
            c6 = fmaf(bv, wp[6], c6); c7 = fmaf(bv, wp[7], c7);
            c8 = fmaf(bv, wp[8], c8); c9 = fmaf(bv, wp[9], c9);
        }
        #pragma unroll
        for (int s = 1; s < 64; s <<= 1) {
            c0 += __shfl_xor(c0, s); c1 += __shfl_xor(c1, s);
            c2 += __shfl_xor(c2, s); c3 += __shfl_xor(c3, s);
            c4 += __shfl_xor(c4, s); c5 += __shfl_xor(c5, s);
            c6 += __shfl_xor(c6, s); c7 += __shfl_xor(c7, s);
            c8 += __shfl_xor(c8, s); c9 += __shfl_xor(c9, s);
        }
        if (lane == 0) {
            wsF[19968 + 0] = LOG2E2 * (c0 + bo1[0]);
            wsF[19968 + 1] = LOG2E2 * (c1 + bo1[1]);
            wsF[19968 + 2] = LOG2E2 * (c2 + bo1[2]);
            wsF[19968 + 3] = LOG2E2 * (c3 + bo1[3]);
            wsF[19968 + 4] = LOG2E2 * (c4 + bo1[4]);
            wsF[19968 + 5] = LOG2E2 * (c5 + bo1[5]);
            wsF[19968 + 6] = LOG2E2 * (c6 + bo1[6]);
            wsF[19968 + 7] = LOG2E2 * (c7 + bo1[7]);
            wsF[19968 + 8] = LOG2E2 * (c8 + bo1[8]);
            wsF[19968 + 9] = LOG2E2 * (c9 + bo1[9]);
        }
    }
}

// 8 tanh for one tile from scalar X and (w,b) quads p0..p3, packed into DST
#define HTILE_S(DST, X) { \
    float h0, h1, h2, h3, h4, h5, h6, h7; \
    TANHS(h0, fmaf(X, p0.x, p0.y)); TANHS(h1, fmaf(X, p0.z, p0.w)); \
    TANHS(h2, fmaf(X, p1.x, p1.y)); TANHS(h3, fmaf(X, p1.z, p1.w)); \
    TANHS(h4, fmaf(X, p2.x, p2.y)); TANHS(h5, fmaf(X, p2.z, p2.w)); \
    TANHS(h6, fmaf(X, p3.x, p3.y)); TANHS(h7, fmaf(X, p3.z, p3.w)); \
    PACK8(DST) \
}
// tail variant: components of float4 X map to v-pairs
#define HTILE_T(DST, X) { \
    float h0, h1, h2, h3, h4, h5, h6, h7; \
    TANHS(h0, fmaf(X.x, p0.x, p0.y)); TANHS(h1, fmaf(X.x, p0.z, p0.w)); \
    TANHS(h2, fmaf(X.y, p1.x, p1.y)); TANHS(h3, fmaf(X.y, p1.z, p1.w)); \
    TANHS(h4, fmaf(X.z, p2.x, p2.y)); TANHS(h5, fmaf(X.z, p2.z, p2.w)); \
    TANHS(h6, fmaf(X.w, p3.x, p3.y)); TANHS(h7, fmaf(X.w, p3.z, p3.w)); \
    PACK8(DST) \
}

// one main step: d = qb+hi4+J, k=0..7; both tiles share (w,b) and W reads
#define MAINSTEP2(J, XA, XB) { \
    const int d_ = qb + hi4 + (J); \
    const float* wb_ = ldsF + d_ * 20; \
    const float4 p0 = *(const float4*)(wb_); \
    const float4 p1 = *(const float4*)(wb_ + 4); \
    const float4 p2 = *(const float4*)(wb_ + 8); \
    const float4 p3 = *(const float4*)(wb_ + 12); \
    short8v av0_, av1_; \
    HTILE_S(av0_, XA) \
    HTILE_S(av1_, XB) \
    const short8v bf_ = *(const short8v*)(ldsU + 6144 + d_ * 88 + meff8); \
    acc0 = __builtin_amdgcn_mfma_f32_16x16x32_bf16(av0_, bf_, acc0, 0, 0, 0); \
    acc1 = __builtin_amdgcn_mfma_f32_16x16x32_bf16(av1_, bf_, acc1, 0, 0, 0); \
}

// tail step for group q: d = qb+hi4+(v>>1), k = 8+(v&1)
#define TAILSTEP2 { \
    const float* tw_ = ldsF + 2560 + q * 64 + hi16; \
    const float4 p0 = *(const float4*)(tw_); \
    const float4 p1 = *(const float4*)(tw_ + 4); \
    const float4 p2 = *(const float4*)(tw_ + 8); \
    const float4 p3 = *(const float4*)(tw_ + 12); \
    short8v av0_, av1_; \
    HTILE_T(av0_, xq0) \
    HTILE_T(av1_, xq1) \
    const short8v bf_ = *(const short8v*)(ldsU + 17408 + q * 320 + hi80 + meff8); \
    acc0 = __builtin_amdgcn_mfma_f32_16x16x32_bf16(av0_, bf_, acc0, 0, 0, 0); \
    acc1 = __builtin_amdgcn_mfma_f32_16x16x32_bf16(av1_, bf_, acc1, 0, 0, 0); \
}

__global__ __launch_bounds__(256, 2)
void kan_main(const float* __restrict__ x, float* __restrict__ ws) {
    __shared__ float4 ldsRaw[2496];            // 39,936 B
    float* ldsF = (float*)ldsRaw;
    const ushort* ldsU = (const ushort*)ldsRaw;

    const int t = threadIdx.x;
    const int rb = blockIdx.x & 255;           // row-block
    const int h  = blockIdx.x >> 8;            // d-half
    {
        const float4* src = (const float4*)(ws + h * 9984);
        for (int i = t; i < 2496; i += 256) ldsRaw[i] = src[i];
    }
    __syncthreads();

    const int lane = t & 63;
    const int wave = t >> 6;
    const int m = lane & 15;                   // A row within tile AND C/D col
    const int hi = lane >> 4;
    const int hi4 = hi * 4, hi16 = hi * 16, hi80 = hi * 80;
    const int meff8 = ((m < 10) ? m : 0) * 8;
    const int rows0 = rb * 128 + wave * 32;
    const float* xr0 = x + (size_t)(rows0 + m) * 256 + h * 128;
    const float* xr1 = xr0 + 16 * 256;

    f32x4 acc0 = {0.f, 0.f, 0.f, 0.f};
    f32x4 acc1 = {0.f, 0.f, 0.f, 0.f};

    #pragma unroll 2
    for (int q = 0; q < 8; ++q) {
        const int qb = q * 16;
        const float4 xq0 = *(const float4*)(xr0 + qb + hi4);
        const float4 xq1 = *(const float4*)(xr1 + qb + hi4);
        MAINSTEP2(0, xq0.x, xq1.x)
        MAINSTEP2(1, xq0.y, xq1.y)
        MAINSTEP2(2, xq0.z, xq1.z)
        MAINSTEP2(3, xq0.w, xq1.w)
        TAILSTEP2
    }

    // store partials: acc[r] = row rows0(+16)+hi4+r, col m
    if (m < 10) {
        float* P = ws + 20480 + (size_t)h * 393216;
        float* pa = P + (size_t)(rows0 + hi4) * 12 + m;
        pa[0] = acc0[0]; pa[12] = acc0[1]; pa[24] = acc0[2]; pa[36] = acc0[3];
        float* pb = P + (size_t)(rows0 + 16 + hi4) * 12 + m;
        pb[0] = acc1[0]; pb[12] = acc1[1]; pb[24] = acc1[2]; pb[36] = acc1[3];
    }
}

#define EPIM(AV, M) { \
    float t_ = fmaf(LOG2E2, (AV), cs[M]); \
    float u_; TANHS(u_, t_); \
    o = fmaf(u_, wo2[M], o); \
}

__global__ void kan_epi(const float* __restrict__ ws, const float* __restrict__ wo2,
                        const float* __restrict__ bo2, float* __restrict__ out) {
    int row = blockIdx.x * 256 + threadIdx.x;
    const float4* Pa = (const float4*)(ws + 20480 + (size_t)row * 12);
    const float4* Pb = (const float4*)(ws + 20480 + 393216 + (size_t)row * 12);
    float4 a0 = Pa[0], a1 = Pa[1], a2 = Pa[2];
    float4 b0 = Pb[0], b1 = Pb[1], b2 = Pb[2];
    const float* cs = ws + 19968;
    float o = bo2[0];
    EPIM(a0.x + b0.x, 0) EPIM(a0.y + b0.y, 1) EPIM(a0.z + b0.z, 2) EPIM(a0.w + b0.w, 3)
    EPIM(a1.x + b1.x, 4) EPIM(a1.y + b1.y, 5) EPIM(a1.z + b1.z, 6) EPIM(a1.w + b1.w, 7)
    EPIM(a2.x + b2.x, 8) EPIM(a2.y + b2.y, 9)
    out[row] = o;
}

extern "C" void kernel_launch(void* const* d_in, const int* in_sizes, int n_in,
                              void* d_out, int out_size, void* d_ws, size_t ws_size,
                              hipStream_t stream) {
    const float* x   = (const float*)d_in[0];
    const float* w1  = (const float*)d_in[1];
    const float* b1  = (const float*)d_in[2];
    const float* w2  = (const float*)d_in[3];
    const float* b2  = (const float*)d_in[4];
    const float* wo1 = (const float*)d_in[5];
    const float* bo1 = (const float*)d_in[6];
    const float* wo2 = (const float*)d_in[7];
    const float* bo2 = (const float*)d_in[8];
    float* out = (float*)d_out;
    float* ws  = (float*)d_ws;

    hipLaunchKernelGGL(kan_prep, dim3(121), dim3(256), 0, stream,
                       w1, b1, w2, b2, wo1, bo1, ws);
    hipLaunchKernelGGL(kan_main, dim3(512), dim3(256), 0, stream, x, ws);
    hipLaunchKernelGGL(kan_epi, dim3(128), dim3(256), 0, stream,
                       ws, wo2, bo2, out);
}

// Round 13
// 45.672 us; speedup vs baseline: 8.6787x; 1.0287x over previous
//
#include <hip/hip_runtime.h>
#include <hip/hip_bf16.h>

// KAN layer: B=32768, D=256, K=10 — MFMA + split-D QUARTERS + 2 row-tiles/wave.
// Round 13: round 12 (split-D halves, 40KB LDS, 2 waves/SIMD) left main ~35us
// vs a ~12-14us issue floor — dependency-stall-bound at 2 waves/SIMD. Quarters
// shrink LDS to 20KB/block -> 4 blocks/CU -> 4 waves/SIMD for 2x latency hiding.
// Per-wave structure unchanged: two 16-row MFMA accumulators share every LDS
// read; per-quarter f32 partials to ws; kan_epi sums 4 + outer tanh + wo2 dot.
//
// slot->kk map (verified r7/r9): main step (d, k=v in 0..7) with d = qb+hi*4+J;
// tail step d = qb+hi*4+(v>>1), k = 8+(v&1). A and B use the same map so the
// HW k-permutation cancels.
//
// ws layout (floats):
//   per quarter qt (at qt*4992):
//     [0,1280)    WB  f32 [64 dl][20]: (w1s,b1s) pairs k=0..7 (16 used)
//     [1280,1536) TWB f32 [4 ql][4 hi][8 v][2]: tail (w,b)
//     [1536,4352) WM  bf16 [64 dl][11 m][8 k] (ushort idx 3072 + dl*88 + m*8 + k)
//     [4352,4992) WTL bf16 [4 ql][4 hi][10 m][8 v] (ushort 8704 + (ql*4+hi)*80 + m*8 + v)
//   [19968,19978) CS f32: cs[m] = LOG2E2*(bo1[m]+sum b2*wo1)
//   [20480, 20480+4*393216) P f32 [4 qt][32768 row][12]

#define LOG2E2 2.885390081777927f   // 2*log2(e)

#if __has_builtin(__builtin_amdgcn_exp2f)
#define EXP2F(x) __builtin_amdgcn_exp2f(x)
#else
#define EXP2F(x) __expf((x) * 0.6931471805599453f)
#endif
#if __has_builtin(__builtin_amdgcn_rcpf)
#define RCPF(x) __builtin_amdgcn_rcpf(x)
#else
#define RCPF(x) (1.0f / (x))
#endif
// tanh(a) with t = 2*log2(e)*a: 1 - 2/(2^t+1)
#define TANHS(DST, T) do { float _e = EXP2F(T); DST = fmaf(-2.0f, RCPF(_e + 1.0f), 1.0f); } while (0)

typedef __attribute__((ext_vector_type(8))) short short8v;
typedef __attribute__((ext_vector_type(4))) float f32x4;
typedef __attribute__((ext_vector_type(4))) unsigned uint4v;

__device__ __forceinline__ unsigned cvt_pk_bf16(float lo, float hi) {
    unsigned r;
    asm("v_cvt_pk_bf16_f32 %0, %1, %2" : "=v"(r) : "v"(lo), "v"(hi));
    return r;
}

#define PACK8(DST) { \
    uint4v _uu; \
    _uu.x = cvt_pk_bf16(h0, h1); \
    _uu.y = cvt_pk_bf16(h2, h3); \
    _uu.z = cvt_pk_bf16(h4, h5); \
    _uu.w = cvt_pk_bf16(h6, h7); \
    DST = __builtin_bit_cast(short8v, _uu); \
}

__device__ __forceinline__ ushort f2bf(float f) {
    union { float f; unsigned u; } a; a.f = f;
    unsigned u = a.u;
    u += 0x7FFF + ((u >> 16) & 1);
    return (ushort)(u >> 16);
}

__global__ void kan_prep(const float* __restrict__ w1, const float* __restrict__ b1,
                         const float* __restrict__ w2, const float* __restrict__ b2,
                         const float* __restrict__ wo1, const float* __restrict__ bo1,
                         float* __restrict__ ws) {
    int gid = blockIdx.x * 256 + threadIdx.x;
    float* wsF = ws;
    ushort* wsU = (ushort*)ws;
    if (gid < 25600) {
        // Wf[d,k,m] = sum_j w2[d,k,j]*wo1[d*10+j, m]
        int m = gid % 10;
        int k = (gid / 10) % 10;
        int d = gid / 100;
        const float* w2p = w2 + d * 100 + k * 10;
        const float* wop = wo1 + d * 100 + m;
        float v = 0.f;
        #pragma unroll
        for (int j = 0; j < 10; ++j) v = fmaf(w2p[j], wop[j * 10], v);
        ushort hv = f2bf(v);
        int qt = d >> 6, dl = d & 63;
        if (k < 8) {
            wsU[qt * 9984 + 3072 + (dl * 11 + m) * 8 + k] = hv;
        } else {
            int ql = (d >> 4) & 3, hi = (d >> 2) & 3, vv = ((d & 3) << 1) | (k - 8);
            wsU[qt * 9984 + 8704 + ((ql * 4 + hi) * 10 + m) * 8 + vv] = hv;
        }
    } else if (gid < 29696) {
        // WB: id = d*16 + r; r = 2v+which, v=0..7
        int id = gid - 25600;
        int d = id >> 4, r = id & 15;
        int v = r >> 1;
        int qt = d >> 6, dl = d & 63;
        wsF[qt * 4992 + dl * 20 + r] = ((r & 1) ? b1 : w1)[d * 10 + v] * LOG2E2;
    } else if (gid < 30720) {
        // TWB: id = slot*2 + which, slot = (qg*4+hi)*8 + v, qg=0..15 global q-group
        int id = gid - 29696;
        int which = id & 1, slot = id >> 1;
        int v = slot & 7, hi = (slot >> 3) & 3, qg = slot >> 5;
        int d = qg * 16 + hi * 4 + (v >> 1);
        int k = 8 + (v & 1);
        int qt = qg >> 2, ql = qg & 3;
        wsF[qt * 4992 + 1280 + ((ql * 4 + hi) * 8 + v) * 2 + which] =
            ((which) ? b1 : w1)[d * 10 + k] * LOG2E2;
    } else if (gid < 30784) {
        // one wave: cs[10]
        int lane = gid - 30720;
        float c0 = 0.f, c1 = 0.f, c2 = 0.f, c3 = 0.f, c4 = 0.f;
        float c5 = 0.f, c6 = 0.f, c7 = 0.f, c8 = 0.f, c9 = 0.f;
        for (int r = lane; r < 2560; r += 64) {
            float bv = b2[r];
            const float* wp = wo1 + r * 10;
            c0 = fmaf(bv, wp[0], c0); c1 = fmaf(bv, wp[1], c1);
            c2 = fmaf(bv, wp[2], c2); c3 = fmaf(bv, wp[3], c3);
            c4 = fmaf(bv, wp[4], c4); c5 = fmaf(bv, wp[5], c5);
            c6 = fmaf(bv, wp[6], c6); c7 = fmaf(bv, wp[7], c7);
            c8 = fmaf(bv, wp[8], c8); c9 = fmaf(bv, wp[9], c9);
        }
        #pragma unroll
        for (int s = 1; s < 64; s <<= 1) {
            c0 += __shfl_xor(c0, s); c1 += __shfl_xor(c1, s);
            c2 += __shfl_xor(c2, s); c3 += __shfl_xor(c3, s);
            c4 += __shfl_xor(c4, s); c5 += __shfl_xor(c5, s);
            c6 += __shfl_xor(c6, s); c7 += __shfl_xor(c7, s);
            c8 += __shfl_xor(c8, s); c9 += __shfl_xor(c9, s);
        }
        if (lane == 0) {
            wsF[19968 + 0] = LOG2E2 * (c0 + bo1[0]);
            wsF[19968 + 1] = LOG2E2 * (c1 + bo1[1]);
            wsF[19968 + 2] = LOG2E2 * (c2 + bo1[2]);
            wsF[19968 + 3] = LOG2E2 * (c3 + bo1[3]);
            wsF[19968 + 4] = LOG2E2 * (c4 + bo1[4]);
            wsF[19968 + 5] = LOG2E2 * (c5 + bo1[5]);
            wsF[19968 + 6] = LOG2E2 * (c6 + bo1[6]);
            wsF[19968 + 7] = LOG2E2 * (c7 + bo1[7]);
            wsF[19968 + 8] = LOG2E2 * (c8 + bo1[8]);
            wsF[19968 + 9] = LOG2E2 * (c9 + bo1[9]);
        }
    }
}

// 8 tanh for one tile from scalar X and (w,b) quads p0..p3, packed into DST
#define HTILE_S(DST, X) { \
    float h0, h1, h2, h3, h4, h5, h6, h7; \
    TANHS(h0, fmaf(X, p0.x, p0.y)); TANHS(h1, fmaf(X, p0.z, p0.w)); \
    TANHS(h2, fmaf(X, p1.x, p1.y)); TANHS(h3, fmaf(X, p1.z, p1.w)); \
    TANHS(h4, fmaf(X, p2.x, p2.y)); TANHS(h5, fmaf(X, p2.z, p2.w)); \
    TANHS(h6, fmaf(X, p3.x, p3.y)); TANHS(h7, fmaf(X, p3.z, p3.w)); \
    PACK8(DST) \
}
// tail variant: components of float4 X map to v-pairs
#define HTILE_T(DST, X) { \
    float h0, h1, h2, h3, h4, h5, h6, h7; \
    TANHS(h0, fmaf(X.x, p0.x, p0.y)); TANHS(h1, fmaf(X.x, p0.z, p0.w)); \
    TANHS(h2, fmaf(X.y, p1.x, p1.y)); TANHS(h3, fmaf(X.y, p1.z, p1.w)); \
    TANHS(h4, fmaf(X.z, p2.x, p2.y)); TANHS(h5, fmaf(X.z, p2.z, p2.w)); \
    TANHS(h6, fmaf(X.w, p3.x, p3.y)); TANHS(h7, fmaf(X.w, p3.z, p3.w)); \
    PACK8(DST) \
}

// one main step: d = qb+hi4+J (local, <64), k=0..7; both tiles share LDS reads
#define MAINSTEP2(J, XA, XB) { \
    const int d_ = qb + hi4 + (J); \
    const float* wb_ = ldsF + d_ * 20; \
    const float4 p0 = *(const float4*)(wb_); \
    const float4 p1 = *(const float4*)(wb_ + 4); \
    const float4 p2 = *(const float4*)(wb_ + 8); \
    const float4 p3 = *(const float4*)(wb_ + 12); \
    short8v av0_, av1_; \
    HTILE_S(av0_, XA) \
    HTILE_S(av1_, XB) \
    const short8v bf_ = *(const short8v*)(ldsU + 3072 + d_ * 88 + meff8); \
    acc0 = __builtin_amdgcn_mfma_f32_16x16x32_bf16(av0_, bf_, acc0, 0, 0, 0); \
    acc1 = __builtin_amdgcn_mfma_f32_16x16x32_bf16(av1_, bf_, acc1, 0, 0, 0); \
}

// tail step for local group q: d = qb+hi4+(v>>1), k = 8+(v&1)
#define TAILSTEP2 { \
    const float* tw_ = ldsF + 1280 + q * 64 + hi16; \
    const float4 p0 = *(const float4*)(tw_); \
    const float4 p1 = *(const float4*)(tw_ + 4); \
    const float4 p2 = *(const float4*)(tw_ + 8); \
    const float4 p3 = *(const float4*)(tw_ + 12); \
    short8v av0_, av1_; \
    HTILE_T(av0_, xq0) \
    HTILE_T(av1_, xq1) \
    const short8v bf_ = *(const short8v*)(ldsU + 8704 + q * 320 + hi80 + meff8); \
    acc0 = __builtin_amdgcn_mfma_f32_16x16x32_bf16(av0_, bf_, acc0, 0, 0, 0); \
    acc1 = __builtin_amdgcn_mfma_f32_16x16x32_bf16(av1_, bf_, acc1, 0, 0, 0); \
}

__global__ __launch_bounds__(256, 4)
void kan_main(const float* __restrict__ x, float* __restrict__ ws) {
    __shared__ float4 ldsRaw[1248];            // 19,968 B -> 4 blocks/CU
    float* ldsF = (float*)ldsRaw;
    const ushort* ldsU = (const ushort*)ldsRaw;

    const int t = threadIdx.x;
    const int rb = blockIdx.x & 255;           // row-block
    const int qt = blockIdx.x >> 8;            // d-quarter (0..3)
    {
        const float4* src = (const float4*)(ws + qt * 4992);
        for (int i = t; i < 1248; i += 256) ldsRaw[i] = src[i];
    }
    __syncthreads();

    const int lane = t & 63;
    const int wave = t >> 6;
    const int m = lane & 15;                   // A row within tile AND C/D col
    const int hi = lane >> 4;
    const int hi4 = hi * 4, hi16 = hi * 16, hi80 = hi * 80;
    const int meff8 = ((m < 10) ? m : 0) * 8;
    const int rows0 = rb * 128 + wave * 32;
    const float* xr0 = x + (size_t)(rows0 + m) * 256 + qt * 64;
    const float* xr1 = xr0 + 16 * 256;

    f32x4 acc0 = {0.f, 0.f, 0.f, 0.f};
    f32x4 acc1 = {0.f, 0.f, 0.f, 0.f};

    #pragma unroll 2
    for (int q = 0; q < 4; ++q) {
        const int qb = q * 16;
        const float4 xq0 = *(const float4*)(xr0 + qb + hi4);
        const float4 xq1 = *(const float4*)(xr1 + qb + hi4);
        MAINSTEP2(0, xq0.x, xq1.x)
        MAINSTEP2(1, xq0.y, xq1.y)
        MAINSTEP2(2, xq0.z, xq1.z)
        MAINSTEP2(3, xq0.w, xq1.w)
        TAILSTEP2
    }

    // store partials: acc[r] = row rows0(+16)+hi4+r, col m
    if (m < 10) {
        float* P = ws + 20480 + (size_t)qt * 393216;
        float* pa = P + (size_t)(rows0 + hi4) * 12 + m;
        pa[0] = acc0[0]; pa[12] = acc0[1]; pa[24] = acc0[2]; pa[36] = acc0[3];
        float* pb = P + (size_t)(rows0 + 16 + hi4) * 12 + m;
        pb[0] = acc1[0]; pb[12] = acc1[1]; pb[24] = acc1[2]; pb[36] = acc1[3];
    }
}

#define EPIM(AV, M) { \
    float t_ = fmaf(LOG2E2, (AV), cs[M]); \
    float u_; TANHS(u_, t_); \
    o = fmaf(u_, wo2[M], o); \
}

__global__ void kan_epi(const float* __restrict__ ws, const float* __restrict__ wo2,
                        const float* __restrict__ bo2, float* __restrict__ out) {
    int row = blockIdx.x * 256 + threadIdx.x;
    const float4* P0 = (const float4*)(ws + 20480 + (size_t)row * 12);
    const float4* P1 = (const float4*)(ws + 20480 + 393216 + (size_t)row * 12);
    const float4* P2 = (const float4*)(ws + 20480 + 2 * 393216 + (size_t)row * 12);
    const float4* P3 = (const float4*)(ws + 20480 + 3 * 393216 + (size_t)row * 12);
    float4 a0 = P0[0], a1 = P0[1], a2 = P0[2];
    float4 b0 = P1[0], b1 = P1[1], b2 = P1[2];
    float4 c0 = P2[0], c1 = P2[1], c2 = P2[2];
    float4 d0 = P3[0], d1 = P3[1], d2 = P3[2];
    const float* cs = ws + 19968;
    float o = bo2[0];
    EPIM((a0.x + b0.x) + (c0.x + d0.x), 0)
    EPIM((a0.y + b0.y) + (c0.y + d0.y), 1)
    EPIM((a0.z + b0.z) + (c0.z + d0.z), 2)
    EPIM((a0.w + b0.w) + (c0.w + d0.w), 3)
    EPIM((a1.x + b1.x) + (c1.x + d1.x), 4)
    EPIM((a1.y + b1.y) + (c1.y + d1.y), 5)
    EPIM((a1.z + b1.z) + (c1.z + d1.z), 6)
    EPIM((a1.w + b1.w) + (c1.w + d1.w), 7)
    EPIM((a2.x + b2.x) + (c2.x + d2.x), 8)
    EPIM((a2.y + b2.y) + (c2.y + d2.y), 9)
    out[row] = o;
}

extern "C" void kernel_launch(void* const* d_in, const int* in_sizes, int n_in,
                              void* d_out, int out_size, void* d_ws, size_t ws_size,
                              hipStream_t stream) {
    const float* x   = (const float*)d_in[0];
    const float* w1  = (const float*)d_in[1];
    const float* b1  = (const float*)d_in[2];
    const float* w2  = (const float*)d_in[3];
    const float* b2  = (const float*)d_in[4];
    const float* wo1 = (const float*)d_in[5];
    const float* bo1 = (const float*)d_in[6];
    const float* wo2 = (const float*)d_in[7];
    const float* bo2 = (const float*)d_in[8];
    float* out = (float*)d_out;
    float* ws  = (float*)d_ws;

    hipLaunchKernelGGL(kan_prep, dim3(121), dim3(256), 0, stream,
                       w1, b1, w2, b2, wo1, bo1, ws);
    hipLaunchKernelGGL(kan_main, dim3(1024), dim3(256), 0, stream, x, ws);
    hipLaunchKernelGGL(kan_epi, dim3(128), dim3(256), 0, stream,
                       ws, wo2, bo2, out);
}